// Round 1
// baseline (1090.652 us; speedup 1.0000x reference)
//
#include <hip/hip_runtime.h>

#define N_NODES 100000
#define N_EDGES 1600000
#define N_GRAPHS 512
#define D_IN 128
#define D_H 64
#define D_OUT 32
#define N_CONV 4
#define BN_EPS 1e-5f
#define NSLOT 32

// ---------------- utility: zero a region (counts + bn stats + pooled) ------
__global__ __launch_bounds__(256) void zero_kernel(int* __restrict__ p, int nwords) {
    int i = blockIdx.x * 256 + threadIdx.x;
    if (i < nwords) p[i] = 0;
}

// ---------------- CSR build ------------------------------------------------
__global__ __launch_bounds__(256) void count_kernel(const int* __restrict__ dst,
                                                    int* __restrict__ counts) {
    int e = blockIdx.x * 256 + threadIdx.x;
    if (e < N_EDGES) atomicAdd(&counts[dst[e]], 1);
}

__global__ __launch_bounds__(1024) void scan_kernel(const int* __restrict__ counts,
                                                    int* __restrict__ offs,
                                                    int* __restrict__ cursor) {
    __shared__ int s[1024];
    int t = threadIdx.x;
    const int chunk = (N_NODES + 1023) / 1024;  // 98
    int lo = t * chunk; if (lo > N_NODES) lo = N_NODES;
    int hi = lo + chunk; if (hi > N_NODES) hi = N_NODES;
    int local = 0;
    for (int i = lo; i < hi; i++) local += counts[i];
    s[t] = local;
    __syncthreads();
    for (int off = 1; off < 1024; off <<= 1) {
        int v = 0;
        if (t >= off) v = s[t - off];
        __syncthreads();
        s[t] += v;
        __syncthreads();
    }
    int run = s[t] - local;  // exclusive
    for (int i = lo; i < hi; i++) {
        offs[i] = run; cursor[i] = run;
        run += counts[i];
    }
    if (t == 1023) offs[N_NODES] = s[1023];
}

__global__ __launch_bounds__(256) void scatter_kernel(const int* __restrict__ src,
                                                      const int* __restrict__ dst,
                                                      int* __restrict__ cursor,
                                                      int* __restrict__ csr) {
    int e = blockIdx.x * 256 + threadIdx.x;
    if (e < N_EDGES) {
        int d = dst[e];
        int pos = atomicAdd(&cursor[d], 1);
        csr[pos] = src[e];
    }
}

// ---------------- GEMM: y = in @ w  (in: N x KD, w: KD x 64) ---------------
template <int KD, int NODES>
__global__ __launch_bounds__(256) void gemm_fc1(const float* __restrict__ in,
                                                const float* __restrict__ w,
                                                float* __restrict__ y) {
    constexpr int NPT = NODES / 16;  // nodes per thread
    __shared__ float lw[KD][64];
    __shared__ float lin[NODES][KD + 1];
    int t = threadIdx.x;
    long base = (long)blockIdx.x * NODES;
    for (int i = t; i < KD * 64; i += 256) lw[i >> 6][i & 63] = w[i];
    for (int i = t; i < NODES * KD; i += 256) {
        int r = i / KD, c = i % KD;
        long n = base + r;
        lin[r][c] = (n < N_NODES) ? in[n * KD + c] : 0.f;
    }
    __syncthreads();
    int cg = t & 15, ng = t >> 4;
    float4 acc[NPT];
#pragma unroll
    for (int j = 0; j < NPT; j++) acc[j] = make_float4(0.f, 0.f, 0.f, 0.f);
    for (int k = 0; k < KD; k++) {
        float4 wv = *(const float4*)&lw[k][cg * 4];
#pragma unroll
        for (int j = 0; j < NPT; j++) {
            float a = lin[ng * NPT + j][k];
            acc[j].x += a * wv.x; acc[j].y += a * wv.y;
            acc[j].z += a * wv.z; acc[j].w += a * wv.w;
        }
    }
#pragma unroll
    for (int j = 0; j < NPT; j++) {
        long n = base + ng * NPT + j;
        if (n < N_NODES) *(float4*)&y[n * 64 + cg * 4] = acc[j];
    }
}

// ---------------- aggregation: agg = y + sum_{nb in N(n)} y[nb] + BN1 stats -
__global__ __launch_bounds__(256) void aggregate(const float* __restrict__ y,
                                                 const int* __restrict__ offs,
                                                 const int* __restrict__ csr,
                                                 float* __restrict__ agg,
                                                 float* __restrict__ bn1p) {
    int t = threadIdx.x;
    int wv = t >> 6, lane = t & 63;
    float s1 = 0.f, s2 = 0.f;
    int nb_base = blockIdx.x * 32 + wv * 8;
    for (int j = 0; j < 8; j++) {
        int n = nb_base + j;
        if (n >= N_NODES) break;
        float sum = y[(long)n * 64 + lane];
        int p0 = offs[n], p1 = offs[n + 1];
        int p = p0;
        for (; p + 3 < p1; p += 4) {
            int i0 = csr[p], i1 = csr[p + 1], i2 = csr[p + 2], i3 = csr[p + 3];
            float v0 = y[(long)i0 * 64 + lane];
            float v1 = y[(long)i1 * 64 + lane];
            float v2 = y[(long)i2 * 64 + lane];
            float v3 = y[(long)i3 * 64 + lane];
            sum += (v0 + v1) + (v2 + v3);
        }
        for (; p < p1; p++) sum += y[(long)csr[p] * 64 + lane];
        agg[(long)n * 64 + lane] = sum;
        s1 += sum; s2 += sum * sum;
    }
    __shared__ float l1[4][64], l2[4][64];
    l1[wv][lane] = s1; l2[wv][lane] = s2;
    __syncthreads();
    if (t < 64) {
        float S = l1[0][t] + l1[1][t] + l1[2][t] + l1[3][t];
        float S2 = l2[0][t] + l2[1][t] + l2[2][t] + l2[3][t];
        int slot = blockIdx.x & (NSLOT - 1);
        atomicAdd(&bn1p[slot * 128 + t], S);
        atomicAdd(&bn1p[slot * 128 + 64 + t], S2);
    }
}

// --------- h2 = relu(BN1(agg)) @ fc2, accumulating BN2 stats ---------------
__global__ __launch_bounds__(256) void gemm_fc2(const float* __restrict__ agg,
                                                const float* __restrict__ w,
                                                const float* __restrict__ bn1p,
                                                const float* __restrict__ g1,
                                                const float* __restrict__ b1,
                                                float* __restrict__ h2,
                                                float* __restrict__ bn2p) {
    __shared__ float lw[64][64];
    __shared__ float lin[64][65];
    __shared__ float sc[64], sh[64];
    int t = threadIdx.x;
    if (t < 64) {
        float S = 0.f, S2 = 0.f;
        for (int s = 0; s < NSLOT; s++) { S += bn1p[s * 128 + t]; S2 += bn1p[s * 128 + 64 + t]; }
        float mean = S * (1.f / N_NODES);
        float var = S2 * (1.f / N_NODES) - mean * mean;
        float r = rsqrtf(var + BN_EPS);
        float scv = g1[t] * r;
        sc[t] = scv; sh[t] = b1[t] - mean * scv;
    }
    for (int i = t; i < 4096; i += 256) lw[i >> 6][i & 63] = w[i];
    __syncthreads();
    long base = (long)blockIdx.x * 64;
    for (int i = t; i < 64 * 64; i += 256) {
        int r = i >> 6, c = i & 63;
        long n = base + r;
        float v = 0.f;
        if (n < N_NODES) {
            v = agg[n * 64 + c] * sc[c] + sh[c];
            v = fmaxf(v, 0.f);
        }
        lin[r][c] = v;
    }
    __syncthreads();
    int cg = t & 15, ng = t >> 4;
    float4 acc[4];
#pragma unroll
    for (int j = 0; j < 4; j++) acc[j] = make_float4(0.f, 0.f, 0.f, 0.f);
    for (int k = 0; k < 64; k++) {
        float4 wv = *(const float4*)&lw[k][cg * 4];
#pragma unroll
        for (int j = 0; j < 4; j++) {
            float a = lin[ng * 4 + j][k];
            acc[j].x += a * wv.x; acc[j].y += a * wv.y;
            acc[j].z += a * wv.z; acc[j].w += a * wv.w;
        }
    }
    float s1[4] = {0.f, 0.f, 0.f, 0.f}, s2[4] = {0.f, 0.f, 0.f, 0.f};
#pragma unroll
    for (int j = 0; j < 4; j++) {
        long n = base + ng * 4 + j;
        if (n < N_NODES) *(float4*)&h2[n * 64 + cg * 4] = acc[j];
        float* a = (float*)&acc[j];
#pragma unroll
        for (int m = 0; m < 4; m++) { s1[m] += a[m]; s2[m] += a[m] * a[m]; }
    }
    __syncthreads();
    float* p1 = &lin[0][0];       // reuse LDS: [16][64]
    float* p2 = p1 + 1024;
#pragma unroll
    for (int m = 0; m < 4; m++) {
        p1[ng * 64 + cg * 4 + m] = s1[m];
        p2[ng * 64 + cg * 4 + m] = s2[m];
    }
    __syncthreads();
    if (t < 64) {
        float S = 0.f, S2 = 0.f;
        for (int gg = 0; gg < 16; gg++) { S += p1[gg * 64 + t]; S2 += p2[gg * 64 + t]; }
        int slot = blockIdx.x & (NSLOT - 1);
        atomicAdd(&bn2p[slot * 128 + t], S);
        atomicAdd(&bn2p[slot * 128 + 64 + t], S2);
    }
}

// --------- hnew = relu(BN2(h2)); pooled[g] += hnew (sorted graph_ids) ------
__global__ __launch_bounds__(256) void bn_relu_pool(const float* __restrict__ h2,
                                                    const float* __restrict__ bn2p,
                                                    const float* __restrict__ g2,
                                                    const float* __restrict__ b2,
                                                    const int* __restrict__ gid,
                                                    float* __restrict__ hnew,
                                                    float* __restrict__ pooled) {
    __shared__ float sc[64], sh[64];
    int t = threadIdx.x;
    if (t < 64) {
        float S = 0.f, S2 = 0.f;
        for (int s = 0; s < NSLOT; s++) { S += bn2p[s * 128 + t]; S2 += bn2p[s * 128 + 64 + t]; }
        float mean = S * (1.f / N_NODES);
        float var = S2 * (1.f / N_NODES) - mean * mean;
        float r = rsqrtf(var + BN_EPS);
        float scv = g2[t] * r;
        sc[t] = scv; sh[t] = b2[t] - mean * scv;
    }
    __syncthreads();
    int c = t & 63, r0 = t >> 6;
    long base = (long)blockIdx.x * 256;
    float ps = 0.f; int gc = -1;
    for (int i = 0; i < 64; i++) {
        long n = base + r0 + 4 * i;
        if (n >= N_NODES) break;
        int g = gid[n];
        float v = h2[n * 64 + c] * sc[c] + sh[c];
        v = fmaxf(v, 0.f);
        hnew[n * 64 + c] = v;
        if (g != gc) {
            if (gc >= 0) atomicAdd(&pooled[(long)gc * 64 + c], ps);
            gc = g; ps = 0.f;
        }
        ps += v;
    }
    if (gc >= 0) atomicAdd(&pooled[(long)gc * 64 + c], ps);
}

// --------- score = sum_l pooled_l @ pred_w_l + pred_b_l --------------------
__global__ __launch_bounds__(256) void score_kernel(const float* __restrict__ pooled,
                                                    const float* __restrict__ pw,
                                                    const float* __restrict__ pb,
                                                    float* __restrict__ out) {
    int idx = blockIdx.x * 256 + threadIdx.x;  // 16384 = 512*32
    int g = idx >> 5, o = idx & 31;
    float acc = 0.f;
    for (int l = 0; l < N_CONV; l++) {
        acc += pb[l * 32 + o];
        const float* pr = pooled + (long)l * N_GRAPHS * 64 + (long)g * 64;
        const float* wr = pw + l * 64 * 32;
        for (int k = 0; k < 64; k++) acc += pr[k] * wr[k * 32 + o];
    }
    out[idx] = acc;
}

extern "C" void kernel_launch(void* const* d_in, const int* in_sizes, int n_in,
                              void* d_out, int out_size, void* d_ws, size_t ws_size,
                              hipStream_t stream) {
    const float* h     = (const float*)d_in[0];
    const int*   src   = (const int*)d_in[1];
    const int*   dst   = (const int*)d_in[2];
    const int*   gid   = (const int*)d_in[3];
    const float* fc1w0 = (const float*)d_in[4];
    const float* fc1w  = (const float*)d_in[5];
    const float* fc2w  = (const float*)d_in[6];
    const float* bn1g  = (const float*)d_in[7];
    const float* bn1b  = (const float*)d_in[8];
    const float* bn2g  = (const float*)d_in[9];
    const float* bn2b  = (const float*)d_in[10];
    const float* pw    = (const float*)d_in[11];
    const float* pb    = (const float*)d_in[12];
    float* out = (float*)d_out;

    char* ws = (char*)d_ws;
    float* X      = (float*)(ws);                    // 100000*64*4 = 25,600,000
    float* Y      = (float*)(ws + 25600000);         // 25,600,000
    int*   counts = (int*)  (ws + 51200000);         // 400,000
    float* bnst   = (float*)(ws + 51600000);         // 4*2*32*128*4 = 131,072
    float* pooled = (float*)(ws + 51731072);         // 4*512*64*4 = 524,288
    int*   offs   = (int*)  (ws + 52255360);         // 400,004 (pad to 400,256)
    int*   cursor = (int*)  (ws + 52655616);         // 400,000
    int*   csr    = (int*)  (ws + 53055616);         // 6,400,000  (end 59,455,616)

    // zero: counts + bn stats + pooled (contiguous region)
    const int zwords = (52255360 - 51200000) / 4;    // 263,840
    zero_kernel<<<(zwords + 255) / 256, 256, 0, stream>>>(counts, zwords);

    count_kernel<<<N_EDGES / 256, 256, 0, stream>>>(dst, counts);
    scan_kernel<<<1, 1024, 0, stream>>>(counts, offs, cursor);
    scatter_kernel<<<N_EDGES / 256, 256, 0, stream>>>(src, dst, cursor, csr);

    for (int l = 0; l < N_CONV; l++) {
        float* bn1p = bnst + (long)l * 8192;
        float* bn2p = bn1p + 4096;
        float* pl = pooled + (long)l * N_GRAPHS * 64;
        if (l == 0)
            gemm_fc1<128, 32><<<3125, 256, 0, stream>>>(h, fc1w0, X);
        else
            gemm_fc1<64, 64><<<1563, 256, 0, stream>>>(Y, fc1w + (long)(l - 1) * 4096, X);
        aggregate<<<3125, 256, 0, stream>>>(X, offs, csr, Y, bn1p);
        gemm_fc2<<<1563, 256, 0, stream>>>(Y, fc2w + (long)l * 4096, bn1p,
                                           bn1g + l * 64, bn1b + l * 64, X, bn2p);
        bn_relu_pool<<<391, 256, 0, stream>>>(X, bn2p, bn2g + l * 64, bn2b + l * 64,
                                              gid, Y, pl);
    }
    score_kernel<<<64, 256, 0, stream>>>(pooled, pw, pb, out);
}

// Round 2
// 867.696 us; speedup vs baseline: 1.2570x; 1.2570x over previous
//
#include <hip/hip_runtime.h>

#define N_NODES 100000
#define N_EDGES 1600000
#define N_GRAPHS 512
#define D_IN 128
#define D_H 64
#define D_OUT 32
#define N_CONV 4
#define BN_EPS 1e-5f
#define NSLOT 32
#define SCAN_BLOCKS 98   // ceil(100000/1024)

// ---------------- utility: zero a region (counts + bn stats + pooled) ------
__global__ __launch_bounds__(256) void zero_kernel(int* __restrict__ p, int nwords) {
    int i = blockIdx.x * 256 + threadIdx.x;
    if (i < nwords) p[i] = 0;
}

// ---------------- CSR build ------------------------------------------------
__global__ __launch_bounds__(256) void count_kernel(const int* __restrict__ dst,
                                                    int* __restrict__ counts) {
    int e = blockIdx.x * 256 + threadIdx.x;
    if (e < N_EDGES) atomicAdd(&counts[dst[e]], 1);
}

// Phase A: per-block reduction of counts -> partials[blockIdx]
__global__ __launch_bounds__(1024) void scanA(const int* __restrict__ counts,
                                              int* __restrict__ partials) {
    int t = threadIdx.x;
    int i = blockIdx.x * 1024 + t;
    int v = (i < N_NODES) ? counts[i] : 0;
    for (int off = 32; off; off >>= 1) v += __shfl_down(v, off, 64);
    __shared__ int red[16];
    if ((t & 63) == 0) red[t >> 6] = v;
    __syncthreads();
    if (t < 16) {
        int s = red[t];
        for (int off = 8; off; off >>= 1) s += __shfl_down(s, off, 16);
        if (t == 0) partials[blockIdx.x] = s;
    }
}

// Phase B: exclusive scan of partials (98 values), write total to offs[N_NODES]
__global__ __launch_bounds__(128) void scanB(int* __restrict__ partials,
                                             int* __restrict__ offs) {
    __shared__ int s[128];
    int t = threadIdx.x;
    int v = (t < SCAN_BLOCKS) ? partials[t] : 0;
    s[t] = v;
    __syncthreads();
    for (int off = 1; off < 128; off <<= 1) {
        int u = (t >= off) ? s[t - off] : 0;
        __syncthreads();
        s[t] += u;
        __syncthreads();
    }
    if (t < SCAN_BLOCKS) partials[t] = s[t] - v;  // exclusive
    if (t == 127) offs[N_NODES] = s[127];
}

// Phase C: block-local exclusive scan + base -> offs, cursor
__global__ __launch_bounds__(1024) void scanC(const int* __restrict__ counts,
                                              const int* __restrict__ partials,
                                              int* __restrict__ offs,
                                              int* __restrict__ cursor) {
    __shared__ int s[1024];
    int t = threadIdx.x;
    int i = blockIdx.x * 1024 + t;
    int v = (i < N_NODES) ? counts[i] : 0;
    s[t] = v;
    __syncthreads();
    for (int off = 1; off < 1024; off <<= 1) {
        int u = (t >= off) ? s[t - off] : 0;
        __syncthreads();
        s[t] += u;
        __syncthreads();
    }
    int excl = s[t] - v + partials[blockIdx.x];
    if (i < N_NODES) { offs[i] = excl; cursor[i] = excl; }
}

__global__ __launch_bounds__(256) void scatter_kernel(const int* __restrict__ src,
                                                      const int* __restrict__ dst,
                                                      int* __restrict__ cursor,
                                                      int* __restrict__ csr) {
    int e = blockIdx.x * 256 + threadIdx.x;
    if (e < N_EDGES) {
        int d = dst[e];
        int pos = atomicAdd(&cursor[d], 1);
        csr[pos] = src[e];
    }
}

// ---------------- GEMM: y = in @ w  (in: N x KD, w: KD x 64) ---------------
template <int KD, int NODES>
__global__ __launch_bounds__(256) void gemm_fc1(const float* __restrict__ in,
                                                const float* __restrict__ w,
                                                float* __restrict__ y) {
    constexpr int NPT = NODES / 16;  // nodes per thread
    __shared__ float lw[KD][64];
    __shared__ float lin[NODES][KD + 1];
    int t = threadIdx.x;
    long base = (long)blockIdx.x * NODES;
    for (int i = t; i < KD * 64; i += 256) lw[i >> 6][i & 63] = w[i];
    for (int i = t; i < NODES * KD; i += 256) {
        int r = i / KD, c = i % KD;
        long n = base + r;
        lin[r][c] = (n < N_NODES) ? in[n * KD + c] : 0.f;
    }
    __syncthreads();
    int cg = t & 15, ng = t >> 4;
    float4 acc[NPT];
#pragma unroll
    for (int j = 0; j < NPT; j++) acc[j] = make_float4(0.f, 0.f, 0.f, 0.f);
    for (int k = 0; k < KD; k++) {
        float4 wv = *(const float4*)&lw[k][cg * 4];
#pragma unroll
        for (int j = 0; j < NPT; j++) {
            float a = lin[ng * NPT + j][k];
            acc[j].x += a * wv.x; acc[j].y += a * wv.y;
            acc[j].z += a * wv.z; acc[j].w += a * wv.w;
        }
    }
#pragma unroll
    for (int j = 0; j < NPT; j++) {
        long n = base + ng * NPT + j;
        if (n < N_NODES) *(float4*)&y[n * 64 + cg * 4] = acc[j];
    }
}

// ---------------- aggregation: agg = y + sum_{nb in N(n)} y[nb] + BN1 stats -
__global__ __launch_bounds__(256) void aggregate(const float* __restrict__ y,
                                                 const int* __restrict__ offs,
                                                 const int* __restrict__ csr,
                                                 float* __restrict__ agg,
                                                 float* __restrict__ bn1p) {
    int t = threadIdx.x;
    int wv = t >> 6, lane = t & 63;
    float s1 = 0.f, s2 = 0.f;
    int nb_base = blockIdx.x * 32 + wv * 8;
    for (int j = 0; j < 8; j++) {
        int n = nb_base + j;
        if (n >= N_NODES) break;
        float sum = y[(long)n * 64 + lane];
        int p0 = offs[n], p1 = offs[n + 1];
        int p = p0;
        for (; p + 3 < p1; p += 4) {
            int i0 = csr[p], i1 = csr[p + 1], i2 = csr[p + 2], i3 = csr[p + 3];
            float v0 = y[(long)i0 * 64 + lane];
            float v1 = y[(long)i1 * 64 + lane];
            float v2 = y[(long)i2 * 64 + lane];
            float v3 = y[(long)i3 * 64 + lane];
            sum += (v0 + v1) + (v2 + v3);
        }
        for (; p < p1; p++) sum += y[(long)csr[p] * 64 + lane];
        agg[(long)n * 64 + lane] = sum;
        s1 += sum; s2 += sum * sum;
    }
    __shared__ float l1[4][64], l2[4][64];
    l1[wv][lane] = s1; l2[wv][lane] = s2;
    __syncthreads();
    if (t < 64) {
        float S = l1[0][t] + l1[1][t] + l1[2][t] + l1[3][t];
        float S2 = l2[0][t] + l2[1][t] + l2[2][t] + l2[3][t];
        int slot = blockIdx.x & (NSLOT - 1);
        atomicAdd(&bn1p[slot * 128 + t], S);
        atomicAdd(&bn1p[slot * 128 + 64 + t], S2);
    }
}

// --------- h2 = relu(BN1(agg)) @ fc2, accumulating BN2 stats ---------------
__global__ __launch_bounds__(256) void gemm_fc2(const float* __restrict__ agg,
                                                const float* __restrict__ w,
                                                const float* __restrict__ bn1p,
                                                const float* __restrict__ g1,
                                                const float* __restrict__ b1,
                                                float* __restrict__ h2,
                                                float* __restrict__ bn2p) {
    __shared__ float lw[64][64];
    __shared__ float lin[64][65];
    __shared__ float sc[64], sh[64];
    int t = threadIdx.x;
    if (t < 64) {
        float S = 0.f, S2 = 0.f;
        for (int s = 0; s < NSLOT; s++) { S += bn1p[s * 128 + t]; S2 += bn1p[s * 128 + 64 + t]; }
        float mean = S * (1.f / N_NODES);
        float var = S2 * (1.f / N_NODES) - mean * mean;
        float r = rsqrtf(var + BN_EPS);
        float scv = g1[t] * r;
        sc[t] = scv; sh[t] = b1[t] - mean * scv;
    }
    for (int i = t; i < 4096; i += 256) lw[i >> 6][i & 63] = w[i];
    __syncthreads();
    long base = (long)blockIdx.x * 64;
    for (int i = t; i < 64 * 64; i += 256) {
        int r = i >> 6, c = i & 63;
        long n = base + r;
        float v = 0.f;
        if (n < N_NODES) {
            v = agg[n * 64 + c] * sc[c] + sh[c];
            v = fmaxf(v, 0.f);
        }
        lin[r][c] = v;
    }
    __syncthreads();
    int cg = t & 15, ng = t >> 4;
    float4 acc[4];
#pragma unroll
    for (int j = 0; j < 4; j++) acc[j] = make_float4(0.f, 0.f, 0.f, 0.f);
    for (int k = 0; k < 64; k++) {
        float4 wv = *(const float4*)&lw[k][cg * 4];
#pragma unroll
        for (int j = 0; j < 4; j++) {
            float a = lin[ng * 4 + j][k];
            acc[j].x += a * wv.x; acc[j].y += a * wv.y;
            acc[j].z += a * wv.z; acc[j].w += a * wv.w;
        }
    }
    float s1[4] = {0.f, 0.f, 0.f, 0.f}, s2[4] = {0.f, 0.f, 0.f, 0.f};
#pragma unroll
    for (int j = 0; j < 4; j++) {
        long n = base + ng * 4 + j;
        if (n < N_NODES) *(float4*)&h2[n * 64 + cg * 4] = acc[j];
        float* a = (float*)&acc[j];
#pragma unroll
        for (int m = 0; m < 4; m++) { s1[m] += a[m]; s2[m] += a[m] * a[m]; }
    }
    __syncthreads();
    float* p1 = &lin[0][0];       // reuse LDS: [16][64]
    float* p2 = p1 + 1024;
#pragma unroll
    for (int m = 0; m < 4; m++) {
        p1[ng * 64 + cg * 4 + m] = s1[m];
        p2[ng * 64 + cg * 4 + m] = s2[m];
    }
    __syncthreads();
    if (t < 64) {
        float S = 0.f, S2 = 0.f;
        for (int gg = 0; gg < 16; gg++) { S += p1[gg * 64 + t]; S2 += p2[gg * 64 + t]; }
        int slot = blockIdx.x & (NSLOT - 1);
        atomicAdd(&bn2p[slot * 128 + t], S);
        atomicAdd(&bn2p[slot * 128 + 64 + t], S2);
    }
}

// --------- hnew = relu(BN2(h2)); pooled[g] += hnew (sorted graph_ids) ------
__global__ __launch_bounds__(256) void bn_relu_pool(const float* __restrict__ h2,
                                                    const float* __restrict__ bn2p,
                                                    const float* __restrict__ g2,
                                                    const float* __restrict__ b2,
                                                    const int* __restrict__ gid,
                                                    float* __restrict__ hnew,
                                                    float* __restrict__ pooled) {
    __shared__ float sc[64], sh[64];
    int t = threadIdx.x;
    if (t < 64) {
        float S = 0.f, S2 = 0.f;
        for (int s = 0; s < NSLOT; s++) { S += bn2p[s * 128 + t]; S2 += bn2p[s * 128 + 64 + t]; }
        float mean = S * (1.f / N_NODES);
        float var = S2 * (1.f / N_NODES) - mean * mean;
        float r = rsqrtf(var + BN_EPS);
        float scv = g2[t] * r;
        sc[t] = scv; sh[t] = b2[t] - mean * scv;
    }
    __syncthreads();
    int c = t & 63, r0 = t >> 6;
    long base = (long)blockIdx.x * 256;
    float ps = 0.f; int gc = -1;
    for (int i = 0; i < 64; i++) {
        long n = base + r0 + 4 * i;
        if (n >= N_NODES) break;
        int g = gid[n];
        float v = h2[n * 64 + c] * sc[c] + sh[c];
        v = fmaxf(v, 0.f);
        hnew[n * 64 + c] = v;
        if (g != gc) {
            if (gc >= 0) atomicAdd(&pooled[(long)gc * 64 + c], ps);
            gc = g; ps = 0.f;
        }
        ps += v;
    }
    if (gc >= 0) atomicAdd(&pooled[(long)gc * 64 + c], ps);
}

// --------- score = sum_l pooled_l @ pred_w_l + pred_b_l --------------------
__global__ __launch_bounds__(256) void score_kernel(const float* __restrict__ pooled,
                                                    const float* __restrict__ pw,
                                                    const float* __restrict__ pb,
                                                    float* __restrict__ out) {
    int idx = blockIdx.x * 256 + threadIdx.x;  // 16384 = 512*32
    int g = idx >> 5, o = idx & 31;
    float acc = 0.f;
    for (int l = 0; l < N_CONV; l++) {
        acc += pb[l * 32 + o];
        const float* pr = pooled + (long)l * N_GRAPHS * 64 + (long)g * 64;
        const float* wr = pw + l * 64 * 32;
        for (int k = 0; k < 64; k++) acc += pr[k] * wr[k * 32 + o];
    }
    out[idx] = acc;
}

extern "C" void kernel_launch(void* const* d_in, const int* in_sizes, int n_in,
                              void* d_out, int out_size, void* d_ws, size_t ws_size,
                              hipStream_t stream) {
    const float* h     = (const float*)d_in[0];
    const int*   src   = (const int*)d_in[1];
    const int*   dst   = (const int*)d_in[2];
    const int*   gid   = (const int*)d_in[3];
    const float* fc1w0 = (const float*)d_in[4];
    const float* fc1w  = (const float*)d_in[5];
    const float* fc2w  = (const float*)d_in[6];
    const float* bn1g  = (const float*)d_in[7];
    const float* bn1b  = (const float*)d_in[8];
    const float* bn2g  = (const float*)d_in[9];
    const float* bn2b  = (const float*)d_in[10];
    const float* pw    = (const float*)d_in[11];
    const float* pb    = (const float*)d_in[12];
    float* out = (float*)d_out;

    char* ws = (char*)d_ws;
    float* X        = (float*)(ws);                    // 100000*64*4 = 25,600,000
    float* Y        = (float*)(ws + 25600000);         // 25,600,000
    int*   counts   = (int*)  (ws + 51200000);         // 400,000
    float* bnst     = (float*)(ws + 51600000);         // 4*2*32*128*4 = 131,072
    float* pooled   = (float*)(ws + 51731072);         // 4*512*64*4 = 524,288
    int*   offs     = (int*)  (ws + 52255360);         // 400,004 (pad to 400,256)
    int*   cursor   = (int*)  (ws + 52655616);         // 400,000
    int*   csr      = (int*)  (ws + 53055616);         // 6,400,000 (end 59,455,616)
    int*   partials = (int*)  (ws + 59455616);         // 128 ints = 512 B

    // zero: counts + bn stats + pooled (contiguous region)
    const int zwords = (52255360 - 51200000) / 4;      // 263,840
    zero_kernel<<<(zwords + 255) / 256, 256, 0, stream>>>(counts, zwords);

    count_kernel<<<N_EDGES / 256, 256, 0, stream>>>(dst, counts);
    scanA<<<SCAN_BLOCKS, 1024, 0, stream>>>(counts, partials);
    scanB<<<1, 128, 0, stream>>>(partials, offs);
    scanC<<<SCAN_BLOCKS, 1024, 0, stream>>>(counts, partials, offs, cursor);
    scatter_kernel<<<N_EDGES / 256, 256, 0, stream>>>(src, dst, cursor, csr);

    for (int l = 0; l < N_CONV; l++) {
        float* bn1p = bnst + (long)l * 8192;
        float* bn2p = bn1p + 4096;
        float* pl = pooled + (long)l * N_GRAPHS * 64;
        if (l == 0)
            gemm_fc1<128, 32><<<3125, 256, 0, stream>>>(h, fc1w0, X);
        else
            gemm_fc1<64, 64><<<1563, 256, 0, stream>>>(Y, fc1w + (long)(l - 1) * 4096, X);
        aggregate<<<3125, 256, 0, stream>>>(X, offs, csr, Y, bn1p);
        gemm_fc2<<<1563, 256, 0, stream>>>(Y, fc2w + (long)l * 4096, bn1p,
                                           bn1g + l * 64, bn1b + l * 64, X, bn2p);
        bn_relu_pool<<<391, 256, 0, stream>>>(X, bn2p, bn2g + l * 64, bn2b + l * 64,
                                              gid, Y, pl);
    }
    score_kernel<<<64, 256, 0, stream>>>(pooled, pw, pb, out);
}

// Round 3
// 731.985 us; speedup vs baseline: 1.4900x; 1.1854x over previous
//
#include <hip/hip_runtime.h>

#define N_NODES 100000
#define N_EDGES 1600000
#define N_GRAPHS 512
#define D_IN 128
#define D_H 64
#define D_OUT 32
#define N_CONV 4
#define BN_EPS 1e-5f
#define NSLOT 32

#define NB 512        // buckets
#define NPB 196       // nodes per bucket (511 buckets used: 510*196=99960, last has 40)
#define NBUSED 511
#define CHUNK 8192    // edges per binned_scatter block
#define MAXE 4096     // max edges per bucket (mean 3136, sigma 56 -> +17 sigma)

// ---------------- utility: zero a region ------------------------------------
__global__ __launch_bounds__(256) void zero_kernel(int* __restrict__ p, int nwords) {
    int i = blockIdx.x * 256 + threadIdx.x;
    if (i < nwords) p[i] = 0;
}

// ---------------- CSR build: bucket histogram -------------------------------
__global__ __launch_bounds__(256) void bucket_count(const int* __restrict__ dst,
                                                    int* __restrict__ bucketCnt) {
    __shared__ int l[NB];
    int t = threadIdx.x;
    for (int i = t; i < NB; i += 256) l[i] = 0;
    __syncthreads();
    long base = (long)blockIdx.x * 4096;
    for (int i = t; i < 4096; i += 256) {
        long e = base + i;
        if (e < N_EDGES) atomicAdd(&l[(unsigned)dst[e] / NPB], 1);
    }
    __syncthreads();
    for (int i = t; i < NB; i += 256) if (l[i]) atomicAdd(&bucketCnt[i], l[i]);
}

// ---------------- bucket offsets scan ---------------------------------------
__global__ __launch_bounds__(512) void bucket_scan(const int* __restrict__ bucketCnt,
                                                   int* __restrict__ bucketOffs,
                                                   int* __restrict__ bucketCur) {
    __shared__ int s[512];
    int t = threadIdx.x;
    int v = bucketCnt[t];
    s[t] = v;
    __syncthreads();
    for (int off = 1; off < 512; off <<= 1) {
        int u = (t >= off) ? s[t - off] : 0;
        __syncthreads();
        s[t] += u;
        __syncthreads();
    }
    int excl = s[t] - v;
    bucketOffs[t] = excl;
    bucketCur[t] = excl;
    if (t == 511) bucketOffs[512] = s[511];
}

// ---------------- binned scatter: LDS counting-sort by bucket, coalesced out -
__global__ __launch_bounds__(256) void binned_scatter(const int* __restrict__ src,
                                                      const int* __restrict__ dst,
                                                      int* __restrict__ bucketCur,
                                                      uint2* __restrict__ pairs) {
    __shared__ uint2 sorted[CHUNK];          // 64 KB
    __shared__ int lcnt[NB], loffs[NB], lcur[NB], gbase[NB];
    __shared__ int ps[256];
    int t = threadIdx.x;
    long e0 = (long)blockIdx.x * CHUNK;
    int nvalid = (int)min((long)CHUNK, (long)N_EDGES - e0);
    for (int i = t; i < NB; i += 256) lcnt[i] = 0;
    __syncthreads();
    for (int i = t; i < nvalid; i += 256)
        atomicAdd(&lcnt[(unsigned)dst[e0 + i] / NPB], 1);
    __syncthreads();
    // 512-entry exclusive scan with 256 threads (2 entries each)
    int a0 = lcnt[2 * t], a1 = lcnt[2 * t + 1];
    ps[t] = a0 + a1;
    __syncthreads();
    for (int off = 1; off < 256; off <<= 1) {
        int u = (t >= off) ? ps[t - off] : 0;
        __syncthreads();
        ps[t] += u;
        __syncthreads();
    }
    int ex = ps[t] - (a0 + a1);
    loffs[2 * t] = ex; loffs[2 * t + 1] = ex + a0;
    lcur[2 * t] = ex;  lcur[2 * t + 1] = ex + a0;
    __syncthreads();
    // reserve global space per bucket
    for (int i = t; i < NB; i += 256) {
        int c = lcnt[i];
        gbase[i] = c ? atomicAdd(&bucketCur[i], c) : 0;
    }
    // scatter into LDS (bucket-sorted)
    for (int i = t; i < nvalid; i += 256) {
        int d = dst[e0 + i];
        int b = (unsigned)d / NPB;
        int pos = atomicAdd(&lcur[b], 1);
        sorted[pos] = make_uint2((unsigned)src[e0 + i], (unsigned)d);
    }
    __syncthreads();
    // coalesced write-out: runs of each bucket are contiguous
    for (int i = t; i < nvalid; i += 256) {
        uint2 pr = sorted[i];
        int b = pr.y / NPB;
        long gpos = (long)gbase[b] + (i - loffs[b]);
        pairs[gpos] = pr;
    }
}

// ---------------- per-bucket CSR finalize (sorted by dst, coalesced) --------
__global__ __launch_bounds__(256) void csr_finalize(const uint2* __restrict__ pairs,
                                                    const int* __restrict__ bucketOffs,
                                                    int* __restrict__ offs,
                                                    int* __restrict__ csr) {
    __shared__ uint2 lp[MAXE];     // 32 KB
    __shared__ int lsrc[MAXE];     // 16 KB
    __shared__ int lcnt[NPB], lofs[NPB + 1], lcur[NPB];
    __shared__ int ls[256];
    int b = blockIdx.x, t = threadIdx.x;
    int e0 = bucketOffs[b], e1 = bucketOffs[b + 1];
    int ne = e1 - e0;
    int n0 = b * NPB;
    int nn = min(NPB, N_NODES - n0);
    for (int i = t; i < ne; i += 256) lp[i] = pairs[e0 + i];
    for (int i = t; i < nn; i += 256) lcnt[i] = 0;
    __syncthreads();
    for (int i = t; i < ne; i += 256) atomicAdd(&lcnt[lp[i].y - n0], 1);
    __syncthreads();
    int v = (t < nn) ? lcnt[t] : 0;
    ls[t] = v;
    __syncthreads();
    for (int off = 1; off < 256; off <<= 1) {
        int u = (t >= off) ? ls[t - off] : 0;
        __syncthreads();
        ls[t] += u;
        __syncthreads();
    }
    if (t < nn) { lofs[t] = ls[t] - v; lcur[t] = ls[t] - v; offs[n0 + t] = e0 + ls[t] - v; }
    if (t == 0 && b == NBUSED - 1) offs[N_NODES] = e1;
    __syncthreads();
    for (int i = t; i < ne; i += 256) {
        int pos = atomicAdd(&lcur[lp[i].y - n0], 1);
        lsrc[pos] = (int)lp[i].x;
    }
    __syncthreads();
    for (int i = t; i < ne; i += 256) csr[e0 + i] = lsrc[i];
}

// ---------------- GEMM: y = in @ w  (in: N x KD, w: KD x 64) ---------------
template <int KD, int NODES>
__global__ __launch_bounds__(256) void gemm_fc1(const float* __restrict__ in,
                                                const float* __restrict__ w,
                                                float* __restrict__ y) {
    constexpr int NPT = NODES / 16;  // nodes per thread
    __shared__ float lw[KD][64];
    __shared__ float lin[NODES][KD + 1];
    int t = threadIdx.x;
    long base = (long)blockIdx.x * NODES;
    for (int i = t; i < KD * 64; i += 256) lw[i >> 6][i & 63] = w[i];
    for (int i = t; i < NODES * KD; i += 256) {
        int r = i / KD, c = i % KD;
        long n = base + r;
        lin[r][c] = (n < N_NODES) ? in[n * KD + c] : 0.f;
    }
    __syncthreads();
    int cg = t & 15, ng = t >> 4;
    float4 acc[NPT];
#pragma unroll
    for (int j = 0; j < NPT; j++) acc[j] = make_float4(0.f, 0.f, 0.f, 0.f);
    for (int k = 0; k < KD; k++) {
        float4 wv = *(const float4*)&lw[k][cg * 4];
#pragma unroll
        for (int j = 0; j < NPT; j++) {
            float a = lin[ng * NPT + j][k];
            acc[j].x += a * wv.x; acc[j].y += a * wv.y;
            acc[j].z += a * wv.z; acc[j].w += a * wv.w;
        }
    }
#pragma unroll
    for (int j = 0; j < NPT; j++) {
        long n = base + ng * NPT + j;
        if (n < N_NODES) *(float4*)&y[n * 64 + cg * 4] = acc[j];
    }
}

// ---------------- aggregation: agg = y + sum_{nb in N(n)} y[nb] + BN1 stats -
__global__ __launch_bounds__(256) void aggregate(const float* __restrict__ y,
                                                 const int* __restrict__ offs,
                                                 const int* __restrict__ csr,
                                                 float* __restrict__ agg,
                                                 float* __restrict__ bn1p) {
    int t = threadIdx.x;
    int wv = t >> 6, lane = t & 63;
    float s1 = 0.f, s2 = 0.f;
    int nb_base = blockIdx.x * 32 + wv * 8;
    for (int j = 0; j < 8; j++) {
        int n = nb_base + j;
        if (n >= N_NODES) break;
        float sum = y[(long)n * 64 + lane];
        int p0 = offs[n], p1 = offs[n + 1];
        int p = p0;
        for (; p + 3 < p1; p += 4) {
            int i0 = csr[p], i1 = csr[p + 1], i2 = csr[p + 2], i3 = csr[p + 3];
            float v0 = y[(long)i0 * 64 + lane];
            float v1 = y[(long)i1 * 64 + lane];
            float v2 = y[(long)i2 * 64 + lane];
            float v3 = y[(long)i3 * 64 + lane];
            sum += (v0 + v1) + (v2 + v3);
        }
        for (; p < p1; p++) sum += y[(long)csr[p] * 64 + lane];
        agg[(long)n * 64 + lane] = sum;
        s1 += sum; s2 += sum * sum;
    }
    __shared__ float l1[4][64], l2[4][64];
    l1[wv][lane] = s1; l2[wv][lane] = s2;
    __syncthreads();
    if (t < 64) {
        float S = l1[0][t] + l1[1][t] + l1[2][t] + l1[3][t];
        float S2 = l2[0][t] + l2[1][t] + l2[2][t] + l2[3][t];
        int slot = blockIdx.x & (NSLOT - 1);
        atomicAdd(&bn1p[slot * 128 + t], S);
        atomicAdd(&bn1p[slot * 128 + 64 + t], S2);
    }
}

// --------- h2 = relu(BN1(agg)) @ fc2, accumulating BN2 stats ---------------
__global__ __launch_bounds__(256) void gemm_fc2(const float* __restrict__ agg,
                                                const float* __restrict__ w,
                                                const float* __restrict__ bn1p,
                                                const float* __restrict__ g1,
                                                const float* __restrict__ b1,
                                                float* __restrict__ h2,
                                                float* __restrict__ bn2p) {
    __shared__ float lw[64][64];
    __shared__ float lin[64][65];
    __shared__ float sc[64], sh[64];
    int t = threadIdx.x;
    if (t < 64) {
        float S = 0.f, S2 = 0.f;
        for (int s = 0; s < NSLOT; s++) { S += bn1p[s * 128 + t]; S2 += bn1p[s * 128 + 64 + t]; }
        float mean = S * (1.f / N_NODES);
        float var = S2 * (1.f / N_NODES) - mean * mean;
        float r = rsqrtf(var + BN_EPS);
        float scv = g1[t] * r;
        sc[t] = scv; sh[t] = b1[t] - mean * scv;
    }
    for (int i = t; i < 4096; i += 256) lw[i >> 6][i & 63] = w[i];
    __syncthreads();
    long base = (long)blockIdx.x * 64;
    for (int i = t; i < 64 * 64; i += 256) {
        int r = i >> 6, c = i & 63;
        long n = base + r;
        float v = 0.f;
        if (n < N_NODES) {
            v = agg[n * 64 + c] * sc[c] + sh[c];
            v = fmaxf(v, 0.f);
        }
        lin[r][c] = v;
    }
    __syncthreads();
    int cg = t & 15, ng = t >> 4;
    float4 acc[4];
#pragma unroll
    for (int j = 0; j < 4; j++) acc[j] = make_float4(0.f, 0.f, 0.f, 0.f);
    for (int k = 0; k < 64; k++) {
        float4 wv = *(const float4*)&lw[k][cg * 4];
#pragma unroll
        for (int j = 0; j < 4; j++) {
            float a = lin[ng * 4 + j][k];
            acc[j].x += a * wv.x; acc[j].y += a * wv.y;
            acc[j].z += a * wv.z; acc[j].w += a * wv.w;
        }
    }
    float s1[4] = {0.f, 0.f, 0.f, 0.f}, s2[4] = {0.f, 0.f, 0.f, 0.f};
#pragma unroll
    for (int j = 0; j < 4; j++) {
        long n = base + ng * 4 + j;
        if (n < N_NODES) *(float4*)&h2[n * 64 + cg * 4] = acc[j];
        float* a = (float*)&acc[j];
#pragma unroll
        for (int m = 0; m < 4; m++) { s1[m] += a[m]; s2[m] += a[m] * a[m]; }
    }
    __syncthreads();
    float* p1 = &lin[0][0];       // reuse LDS: [16][64]
    float* p2 = p1 + 1024;
#pragma unroll
    for (int m = 0; m < 4; m++) {
        p1[ng * 64 + cg * 4 + m] = s1[m];
        p2[ng * 64 + cg * 4 + m] = s2[m];
    }
    __syncthreads();
    if (t < 64) {
        float S = 0.f, S2 = 0.f;
        for (int gg = 0; gg < 16; gg++) { S += p1[gg * 64 + t]; S2 += p2[gg * 64 + t]; }
        int slot = blockIdx.x & (NSLOT - 1);
        atomicAdd(&bn2p[slot * 128 + t], S);
        atomicAdd(&bn2p[slot * 128 + 64 + t], S2);
    }
}

// --------- hnew = relu(BN2(h2)); pooled[g] += hnew (sorted graph_ids) ------
__global__ __launch_bounds__(256) void bn_relu_pool(const float* __restrict__ h2,
                                                    const float* __restrict__ bn2p,
                                                    const float* __restrict__ g2,
                                                    const float* __restrict__ b2,
                                                    const int* __restrict__ gid,
                                                    float* __restrict__ hnew,
                                                    float* __restrict__ pooled) {
    __shared__ float sc[64], sh[64];
    int t = threadIdx.x;
    if (t < 64) {
        float S = 0.f, S2 = 0.f;
        for (int s = 0; s < NSLOT; s++) { S += bn2p[s * 128 + t]; S2 += bn2p[s * 128 + 64 + t]; }
        float mean = S * (1.f / N_NODES);
        float var = S2 * (1.f / N_NODES) - mean * mean;
        float r = rsqrtf(var + BN_EPS);
        float scv = g2[t] * r;
        sc[t] = scv; sh[t] = b2[t] - mean * scv;
    }
    __syncthreads();
    int c = t & 63, r0 = t >> 6;
    long base = (long)blockIdx.x * 256;
    float ps = 0.f; int gc = -1;
    for (int i = 0; i < 64; i++) {
        long n = base + r0 + 4 * i;
        if (n >= N_NODES) break;
        int g = gid[n];
        float v = h2[n * 64 + c] * sc[c] + sh[c];
        v = fmaxf(v, 0.f);
        hnew[n * 64 + c] = v;
        if (g != gc) {
            if (gc >= 0) atomicAdd(&pooled[(long)gc * 64 + c], ps);
            gc = g; ps = 0.f;
        }
        ps += v;
    }
    if (gc >= 0) atomicAdd(&pooled[(long)gc * 64 + c], ps);
}

// --------- score = sum_l pooled_l @ pred_w_l + pred_b_l --------------------
__global__ __launch_bounds__(256) void score_kernel(const float* __restrict__ pooled,
                                                    const float* __restrict__ pw,
                                                    const float* __restrict__ pb,
                                                    float* __restrict__ out) {
    int idx = blockIdx.x * 256 + threadIdx.x;  // 16384 = 512*32
    int g = idx >> 5, o = idx & 31;
    float acc = 0.f;
    for (int l = 0; l < N_CONV; l++) {
        acc += pb[l * 32 + o];
        const float* pr = pooled + (long)l * N_GRAPHS * 64 + (long)g * 64;
        const float* wr = pw + l * 64 * 32;
        for (int k = 0; k < 64; k++) acc += pr[k] * wr[k * 32 + o];
    }
    out[idx] = acc;
}

extern "C" void kernel_launch(void* const* d_in, const int* in_sizes, int n_in,
                              void* d_out, int out_size, void* d_ws, size_t ws_size,
                              hipStream_t stream) {
    const float* h     = (const float*)d_in[0];
    const int*   src   = (const int*)d_in[1];
    const int*   dst   = (const int*)d_in[2];
    const int*   gid   = (const int*)d_in[3];
    const float* fc1w0 = (const float*)d_in[4];
    const float* fc1w  = (const float*)d_in[5];
    const float* fc2w  = (const float*)d_in[6];
    const float* bn1g  = (const float*)d_in[7];
    const float* bn1b  = (const float*)d_in[8];
    const float* bn2g  = (const float*)d_in[9];
    const float* bn2b  = (const float*)d_in[10];
    const float* pw    = (const float*)d_in[11];
    const float* pb    = (const float*)d_in[12];
    float* out = (float*)d_out;

    char* ws = (char*)d_ws;
    float* X         = (float*)(ws);                 // 25,600,000
    float* Y         = (float*)(ws + 25600000);      // 25,600,000
    uint2* pairs     = (uint2*)(ws + 25600000);      // 12,800,000 (aliases Y; dead before layer 0 aggregate writes Y)
    float* bnst      = (float*)(ws + 51200000);      // 131,072
    float* pooled    = (float*)(ws + 51331072);      // 524,288
    int*   bucketCnt = (int*)  (ws + 51855360);      // 2,048
    int*   bucketOffs= (int*)  (ws + 51857408);      // 2,052
    int*   bucketCur = (int*)  (ws + 51859460);      // 2,048
    int*   offs      = (int*)  (ws + 51861508);      // 400,004
    int*   csr       = (int*)  (ws + 52261512);      // 6,400,000 (end 58,661,512)

    // zero: bnst + pooled + bucketCnt (contiguous: 51,200,000 .. 51,857,408)
    const int zwords = (51857408 - 51200000) / 4;    // 164,352
    zero_kernel<<<(zwords + 255) / 256, 256, 0, stream>>>((int*)bnst, zwords);

    bucket_count<<<(N_EDGES + 4095) / 4096, 256, 0, stream>>>(dst, bucketCnt);
    bucket_scan<<<1, 512, 0, stream>>>(bucketCnt, bucketOffs, bucketCur);
    binned_scatter<<<(N_EDGES + CHUNK - 1) / CHUNK, 256, 0, stream>>>(src, dst, bucketCur, pairs);
    csr_finalize<<<NBUSED, 256, 0, stream>>>(pairs, bucketOffs, offs, csr);

    for (int l = 0; l < N_CONV; l++) {
        float* bn1p = bnst + (long)l * 8192;
        float* bn2p = bn1p + 4096;
        float* pl = pooled + (long)l * N_GRAPHS * 64;
        if (l == 0)
            gemm_fc1<128, 32><<<3125, 256, 0, stream>>>(h, fc1w0, X);
        else
            gemm_fc1<64, 64><<<1563, 256, 0, stream>>>(Y, fc1w + (long)(l - 1) * 4096, X);
        aggregate<<<3125, 256, 0, stream>>>(X, offs, csr, Y, bn1p);
        gemm_fc2<<<1563, 256, 0, stream>>>(Y, fc2w + (long)l * 4096, bn1p,
                                           bn1g + l * 64, bn1b + l * 64, X, bn2p);
        bn_relu_pool<<<391, 256, 0, stream>>>(X, bn2p, bn2g + l * 64, bn2b + l * 64,
                                              gid, Y, pl);
    }
    score_kernel<<<64, 256, 0, stream>>>(pooled, pw, pb, out);
}

// Round 4
// 693.211 us; speedup vs baseline: 1.5733x; 1.0559x over previous
//
#include <hip/hip_runtime.h>

#define N_NODES 100000
#define N_EDGES 1600000
#define N_GRAPHS 512
#define D_IN 128
#define D_H 64
#define D_OUT 32
#define N_CONV 4
#define BN_EPS 1e-5f
#define NSLOT 32

#define NB 512        // buckets
#define NPB 196       // nodes per bucket
#define NBUSED 511
#define CHUNK 8192    // edges per binned_scatter block
#define MAXE 4096     // max edges per bucket (mean 3136)

typedef unsigned short ushort_t;
typedef unsigned int uint_t;

__device__ inline float b2f(ushort_t u) {
    union { uint_t i; float f; } c; c.i = ((uint_t)u) << 16; return c.f;
}
__device__ inline ushort_t f2b(float f) {
    union { uint_t i; float f; } c; c.f = f;
    uint_t r = (c.i + 0x7fffu + ((c.i >> 16) & 1u)) >> 16;
    return (ushort_t)r;
}

// ---------------- utility: zero a region ------------------------------------
__global__ __launch_bounds__(256) void zero_kernel(int* __restrict__ p, int nwords) {
    int i = blockIdx.x * 256 + threadIdx.x;
    if (i < nwords) p[i] = 0;
}

// ---------------- CSR build: bucket histogram -------------------------------
__global__ __launch_bounds__(256) void bucket_count(const int* __restrict__ dst,
                                                    int* __restrict__ bucketCnt) {
    __shared__ int l[NB];
    int t = threadIdx.x;
    for (int i = t; i < NB; i += 256) l[i] = 0;
    __syncthreads();
    long base = (long)blockIdx.x * 4096;
    for (int i = t; i < 4096; i += 256) {
        long e = base + i;
        if (e < N_EDGES) atomicAdd(&l[(unsigned)dst[e] / NPB], 1);
    }
    __syncthreads();
    for (int i = t; i < NB; i += 256) if (l[i]) atomicAdd(&bucketCnt[i], l[i]);
}

// ---------------- bucket offsets scan ---------------------------------------
__global__ __launch_bounds__(512) void bucket_scan(const int* __restrict__ bucketCnt,
                                                   int* __restrict__ bucketOffs,
                                                   int* __restrict__ bucketCur) {
    __shared__ int s[512];
    int t = threadIdx.x;
    int v = bucketCnt[t];
    s[t] = v;
    __syncthreads();
    for (int off = 1; off < 512; off <<= 1) {
        int u = (t >= off) ? s[t - off] : 0;
        __syncthreads();
        s[t] += u;
        __syncthreads();
    }
    int excl = s[t] - v;
    bucketOffs[t] = excl;
    bucketCur[t] = excl;
    if (t == 511) bucketOffs[512] = s[511];
}

// ---------------- binned scatter: LDS counting-sort by bucket ----------------
__global__ __launch_bounds__(256) void binned_scatter(const int* __restrict__ src,
                                                      const int* __restrict__ dst,
                                                      int* __restrict__ bucketCur,
                                                      uint2* __restrict__ pairs) {
    __shared__ uint2 sorted[CHUNK];          // 64 KB
    __shared__ int lcnt[NB], loffs[NB], lcur[NB], gbase[NB];
    __shared__ int ps[256];
    int t = threadIdx.x;
    long e0 = (long)blockIdx.x * CHUNK;
    int nvalid = (int)min((long)CHUNK, (long)N_EDGES - e0);
    for (int i = t; i < NB; i += 256) lcnt[i] = 0;
    __syncthreads();
    for (int i = t; i < nvalid; i += 256)
        atomicAdd(&lcnt[(unsigned)dst[e0 + i] / NPB], 1);
    __syncthreads();
    int a0 = lcnt[2 * t], a1 = lcnt[2 * t + 1];
    ps[t] = a0 + a1;
    __syncthreads();
    for (int off = 1; off < 256; off <<= 1) {
        int u = (t >= off) ? ps[t - off] : 0;
        __syncthreads();
        ps[t] += u;
        __syncthreads();
    }
    int ex = ps[t] - (a0 + a1);
    loffs[2 * t] = ex; loffs[2 * t + 1] = ex + a0;
    lcur[2 * t] = ex;  lcur[2 * t + 1] = ex + a0;
    __syncthreads();
    for (int i = t; i < NB; i += 256) {
        int c = lcnt[i];
        gbase[i] = c ? atomicAdd(&bucketCur[i], c) : 0;
    }
    for (int i = t; i < nvalid; i += 256) {
        int d = dst[e0 + i];
        int b = (unsigned)d / NPB;
        int pos = atomicAdd(&lcur[b], 1);
        sorted[pos] = make_uint2((unsigned)src[e0 + i], (unsigned)d);
    }
    __syncthreads();
    for (int i = t; i < nvalid; i += 256) {
        uint2 pr = sorted[i];
        int b = pr.y / NPB;
        long gpos = (long)gbase[b] + (i - loffs[b]);
        pairs[gpos] = pr;
    }
}

// ---------------- per-bucket CSR finalize -----------------------------------
__global__ __launch_bounds__(256) void csr_finalize(const uint2* __restrict__ pairs,
                                                    const int* __restrict__ bucketOffs,
                                                    int* __restrict__ offs,
                                                    int* __restrict__ csr) {
    __shared__ uint2 lp[MAXE];     // 32 KB
    __shared__ int lsrc[MAXE];     // 16 KB
    __shared__ int lcnt[NPB], lofs[NPB + 1], lcur[NPB];
    __shared__ int ls[256];
    int b = blockIdx.x, t = threadIdx.x;
    int e0 = bucketOffs[b], e1 = bucketOffs[b + 1];
    int ne = e1 - e0;
    int n0 = b * NPB;
    int nn = min(NPB, N_NODES - n0);
    for (int i = t; i < ne; i += 256) lp[i] = pairs[e0 + i];
    for (int i = t; i < nn; i += 256) lcnt[i] = 0;
    __syncthreads();
    for (int i = t; i < ne; i += 256) atomicAdd(&lcnt[lp[i].y - n0], 1);
    __syncthreads();
    int v = (t < nn) ? lcnt[t] : 0;
    ls[t] = v;
    __syncthreads();
    for (int off = 1; off < 256; off <<= 1) {
        int u = (t >= off) ? ls[t - off] : 0;
        __syncthreads();
        ls[t] += u;
        __syncthreads();
    }
    if (t < nn) { lofs[t] = ls[t] - v; lcur[t] = ls[t] - v; offs[n0 + t] = e0 + ls[t] - v; }
    if (t == 0 && b == NBUSED - 1) offs[N_NODES] = e1;
    __syncthreads();
    for (int i = t; i < ne; i += 256) {
        int pos = atomicAdd(&lcur[lp[i].y - n0], 1);
        lsrc[pos] = (int)lp[i].x;
    }
    __syncthreads();
    for (int i = t; i < ne; i += 256) csr[e0 + i] = lsrc[i];
}

// ------------- GEMM layer0: y16 = h(f32, N x 128) @ w -> bf16 ---------------
__global__ __launch_bounds__(256) void gemm_fc1_f32(const float* __restrict__ in,
                                                    const float* __restrict__ w,
                                                    ushort_t* __restrict__ y16) {
    __shared__ float lw[128][64];
    __shared__ float lin[32][129];
    int t = threadIdx.x;
    long base = (long)blockIdx.x * 32;
    for (int i = t; i < 128 * 64; i += 256) lw[i >> 6][i & 63] = w[i];
    for (int i = t; i < 32 * 128; i += 256) {
        int r = i >> 7, c = i & 127;
        long n = base + r;
        lin[r][c] = (n < N_NODES) ? in[n * 128 + c] : 0.f;
    }
    __syncthreads();
    int cg = t & 15, ng = t >> 4;
    float4 acc[2];
#pragma unroll
    for (int j = 0; j < 2; j++) acc[j] = make_float4(0.f, 0.f, 0.f, 0.f);
    for (int k = 0; k < 128; k++) {
        float4 wv = *(const float4*)&lw[k][cg * 4];
#pragma unroll
        for (int j = 0; j < 2; j++) {
            float a = lin[ng * 2 + j][k];
            acc[j].x += a * wv.x; acc[j].y += a * wv.y;
            acc[j].z += a * wv.z; acc[j].w += a * wv.w;
        }
    }
#pragma unroll
    for (int j = 0; j < 2; j++) {
        long n = base + ng * 2 + j;
        if (n < N_NODES) {
            uint2 o;
            o.x = (uint_t)f2b(acc[j].x) | ((uint_t)f2b(acc[j].y) << 16);
            o.y = (uint_t)f2b(acc[j].z) | ((uint_t)f2b(acc[j].w) << 16);
            *(uint2*)&y16[n * 64 + cg * 4] = o;
        }
    }
}

// ------------- GEMM layers 1+: y16 = hnew16(bf16, N x 64) @ w -> bf16 -------
__global__ __launch_bounds__(256) void gemm_fc1_bf16(const ushort_t* __restrict__ in,
                                                     const float* __restrict__ w,
                                                     ushort_t* __restrict__ y16) {
    __shared__ float lw[64][64];
    __shared__ float lin[64][65];
    int t = threadIdx.x;
    long base = (long)blockIdx.x * 64;
    for (int i = t; i < 64 * 64; i += 256) lw[i >> 6][i & 63] = w[i];
    for (int i = t; i < 64 * 32; i += 256) {
        int r = i >> 5, cp = i & 31;
        long n = base + r;
        uint_t v = (n < N_NODES) ? ((const uint_t*)in)[n * 32 + cp] : 0;
        lin[r][2 * cp]     = b2f((ushort_t)(v & 0xffff));
        lin[r][2 * cp + 1] = b2f((ushort_t)(v >> 16));
    }
    __syncthreads();
    int cg = t & 15, ng = t >> 4;
    float4 acc[4];
#pragma unroll
    for (int j = 0; j < 4; j++) acc[j] = make_float4(0.f, 0.f, 0.f, 0.f);
    for (int k = 0; k < 64; k++) {
        float4 wv = *(const float4*)&lw[k][cg * 4];
#pragma unroll
        for (int j = 0; j < 4; j++) {
            float a = lin[ng * 4 + j][k];
            acc[j].x += a * wv.x; acc[j].y += a * wv.y;
            acc[j].z += a * wv.z; acc[j].w += a * wv.w;
        }
    }
#pragma unroll
    for (int j = 0; j < 4; j++) {
        long n = base + ng * 4 + j;
        if (n < N_NODES) {
            uint2 o;
            o.x = (uint_t)f2b(acc[j].x) | ((uint_t)f2b(acc[j].y) << 16);
            o.y = (uint_t)f2b(acc[j].z) | ((uint_t)f2b(acc[j].w) << 16);
            *(uint2*)&y16[n * 64 + cg * 4] = o;
        }
    }
}

// ------- aggregation: agg(f32) = y16 + sum_nb y16[nb] + BN1 stats -----------
__global__ __launch_bounds__(256) void aggregate(const ushort_t* __restrict__ y16,
                                                 const int* __restrict__ offs,
                                                 const int* __restrict__ csr,
                                                 float* __restrict__ agg,
                                                 float* __restrict__ bn1p) {
    int t = threadIdx.x;
    int wv = t >> 6, lane = t & 63;
    float s1 = 0.f, s2 = 0.f;
    int nb_base = blockIdx.x * 32 + wv * 8;
    for (int j = 0; j < 8; j++) {
        int n = nb_base + j;
        if (n >= N_NODES) break;
        float sum = b2f(y16[(long)n * 64 + lane]);
        int p0 = offs[n], p1 = offs[n + 1];
        int p = p0;
        for (; p + 3 < p1; p += 4) {
            int i0 = csr[p], i1 = csr[p + 1], i2 = csr[p + 2], i3 = csr[p + 3];
            float v0 = b2f(y16[(long)i0 * 64 + lane]);
            float v1 = b2f(y16[(long)i1 * 64 + lane]);
            float v2 = b2f(y16[(long)i2 * 64 + lane]);
            float v3 = b2f(y16[(long)i3 * 64 + lane]);
            sum += (v0 + v1) + (v2 + v3);
        }
        for (; p < p1; p++) sum += b2f(y16[(long)csr[p] * 64 + lane]);
        agg[(long)n * 64 + lane] = sum;
        s1 += sum; s2 += sum * sum;
    }
    __shared__ float l1[4][64], l2[4][64];
    l1[wv][lane] = s1; l2[wv][lane] = s2;
    __syncthreads();
    if (t < 64) {
        float S = l1[0][t] + l1[1][t] + l1[2][t] + l1[3][t];
        float S2 = l2[0][t] + l2[1][t] + l2[2][t] + l2[3][t];
        int slot = blockIdx.x & (NSLOT - 1);
        atomicAdd(&bn1p[slot * 128 + t], S);
        atomicAdd(&bn1p[slot * 128 + 64 + t], S2);
    }
}

// --------- h2(bf16) = relu(BN1(agg)) @ fc2, accumulating BN2 stats ----------
__global__ __launch_bounds__(256) void gemm_fc2(const float* __restrict__ agg,
                                                const float* __restrict__ w,
                                                const float* __restrict__ bn1p,
                                                const float* __restrict__ g1,
                                                const float* __restrict__ b1,
                                                ushort_t* __restrict__ h2,
                                                float* __restrict__ bn2p) {
    __shared__ float lw[64][64];
    __shared__ float lin[64][65];
    __shared__ float sc[64], sh[64];
    int t = threadIdx.x;
    if (t < 64) {
        float S = 0.f, S2 = 0.f;
        for (int s = 0; s < NSLOT; s++) { S += bn1p[s * 128 + t]; S2 += bn1p[s * 128 + 64 + t]; }
        float mean = S * (1.f / N_NODES);
        float var = S2 * (1.f / N_NODES) - mean * mean;
        float r = rsqrtf(var + BN_EPS);
        float scv = g1[t] * r;
        sc[t] = scv; sh[t] = b1[t] - mean * scv;
    }
    for (int i = t; i < 4096; i += 256) lw[i >> 6][i & 63] = w[i];
    __syncthreads();
    long base = (long)blockIdx.x * 64;
    for (int i = t; i < 64 * 64; i += 256) {
        int r = i >> 6, c = i & 63;
        long n = base + r;
        float v = 0.f;
        if (n < N_NODES) {
            v = agg[n * 64 + c] * sc[c] + sh[c];
            v = fmaxf(v, 0.f);
        }
        lin[r][c] = v;
    }
    __syncthreads();
    int cg = t & 15, ng = t >> 4;
    float4 acc[4];
#pragma unroll
    for (int j = 0; j < 4; j++) acc[j] = make_float4(0.f, 0.f, 0.f, 0.f);
    for (int k = 0; k < 64; k++) {
        float4 wv = *(const float4*)&lw[k][cg * 4];
#pragma unroll
        for (int j = 0; j < 4; j++) {
            float a = lin[ng * 4 + j][k];
            acc[j].x += a * wv.x; acc[j].y += a * wv.y;
            acc[j].z += a * wv.z; acc[j].w += a * wv.w;
        }
    }
    float s1[4] = {0.f, 0.f, 0.f, 0.f}, s2[4] = {0.f, 0.f, 0.f, 0.f};
#pragma unroll
    for (int j = 0; j < 4; j++) {
        long n = base + ng * 4 + j;
        if (n < N_NODES) {
            uint2 o;
            o.x = (uint_t)f2b(acc[j].x) | ((uint_t)f2b(acc[j].y) << 16);
            o.y = (uint_t)f2b(acc[j].z) | ((uint_t)f2b(acc[j].w) << 16);
            *(uint2*)&h2[n * 64 + cg * 4] = o;
        }
        float* a = (float*)&acc[j];
#pragma unroll
        for (int m = 0; m < 4; m++) { s1[m] += a[m]; s2[m] += a[m] * a[m]; }
    }
    __syncthreads();
    float* p1 = &lin[0][0];       // reuse LDS: [16][64]
    float* p2 = p1 + 1024;
#pragma unroll
    for (int m = 0; m < 4; m++) {
        p1[ng * 64 + cg * 4 + m] = s1[m];
        p2[ng * 64 + cg * 4 + m] = s2[m];
    }
    __syncthreads();
    if (t < 64) {
        float S = 0.f, S2 = 0.f;
        for (int gg = 0; gg < 16; gg++) { S += p1[gg * 64 + t]; S2 += p2[gg * 64 + t]; }
        int slot = blockIdx.x & (NSLOT - 1);
        atomicAdd(&bn2p[slot * 128 + t], S);
        atomicAdd(&bn2p[slot * 128 + 64 + t], S2);
    }
}

// --- hnew16 = relu(BN2(h2_16)); pooled[g] += hnew (sorted graph_ids) --------
__global__ __launch_bounds__(256) void bn_relu_pool(const ushort_t* __restrict__ h2,
                                                    const float* __restrict__ bn2p,
                                                    const float* __restrict__ g2,
                                                    const float* __restrict__ b2,
                                                    const int* __restrict__ gid,
                                                    ushort_t* __restrict__ hnew,
                                                    float* __restrict__ pooled) {
    __shared__ float sc[64], sh[64];
    int t = threadIdx.x;
    if (t < 64) {
        float S = 0.f, S2 = 0.f;
        for (int s = 0; s < NSLOT; s++) { S += bn2p[s * 128 + t]; S2 += bn2p[s * 128 + 64 + t]; }
        float mean = S * (1.f / N_NODES);
        float var = S2 * (1.f / N_NODES) - mean * mean;
        float r = rsqrtf(var + BN_EPS);
        float scv = g2[t] * r;
        sc[t] = scv; sh[t] = b2[t] - mean * scv;
    }
    __syncthreads();
    int c = t & 63, r0 = t >> 6;
    long base = (long)blockIdx.x * 256;
    float ps = 0.f; int gc = -1;
    for (int i = 0; i < 64; i++) {
        long n = base + r0 + 4 * i;
        if (n >= N_NODES) break;
        int g = gid[n];
        float v = b2f(h2[n * 64 + c]) * sc[c] + sh[c];
        v = fmaxf(v, 0.f);
        hnew[n * 64 + c] = f2b(v);
        if (g != gc) {
            if (gc >= 0) atomicAdd(&pooled[(long)gc * 64 + c], ps);
            gc = g; ps = 0.f;
        }
        ps += v;
    }
    if (gc >= 0) atomicAdd(&pooled[(long)gc * 64 + c], ps);
}

// --------- score = sum_l pooled_l @ pred_w_l + pred_b_l --------------------
__global__ __launch_bounds__(256) void score_kernel(const float* __restrict__ pooled,
                                                    const float* __restrict__ pw,
                                                    const float* __restrict__ pb,
                                                    float* __restrict__ out) {
    int idx = blockIdx.x * 256 + threadIdx.x;  // 16384 = 512*32
    int g = idx >> 5, o = idx & 31;
    float acc = 0.f;
    for (int l = 0; l < N_CONV; l++) {
        acc += pb[l * 32 + o];
        const float* pr = pooled + (long)l * N_GRAPHS * 64 + (long)g * 64;
        const float* wr = pw + l * 64 * 32;
        for (int k = 0; k < 64; k++) acc += pr[k] * wr[k * 32 + o];
    }
    out[idx] = acc;
}

extern "C" void kernel_launch(void* const* d_in, const int* in_sizes, int n_in,
                              void* d_out, int out_size, void* d_ws, size_t ws_size,
                              hipStream_t stream) {
    const float* h     = (const float*)d_in[0];
    const int*   src   = (const int*)d_in[1];
    const int*   dst   = (const int*)d_in[2];
    const int*   gid   = (const int*)d_in[3];
    const float* fc1w0 = (const float*)d_in[4];
    const float* fc1w  = (const float*)d_in[5];
    const float* fc2w  = (const float*)d_in[6];
    const float* bn1g  = (const float*)d_in[7];
    const float* bn1b  = (const float*)d_in[8];
    const float* bn2g  = (const float*)d_in[9];
    const float* bn2b  = (const float*)d_in[10];
    const float* pw    = (const float*)d_in[11];
    const float* pb    = (const float*)d_in[12];
    float* out = (float*)d_out;

    char* ws = (char*)d_ws;
    float*    A_f32   = (float*)   (ws);              // agg f32: 25,600,000
    uint2*    pairs   = (uint2*)   (ws);              // 12,800,000 (aliases A_f32; dead before layer-0 aggregate)
    ushort_t* X16     = (ushort_t*)(ws + 25600000);   // y/h2 bf16: 12,800,000
    ushort_t* H16     = (ushort_t*)(ws + 38400000);   // hnew bf16: 12,800,000
    float*    bnst    = (float*)   (ws + 51200000);   // 131,072
    float*    pooled  = (float*)   (ws + 51331072);   // 524,288
    int*   bucketCnt  = (int*)     (ws + 51855360);   // 2,048
    int*   bucketOffs = (int*)     (ws + 51857408);   // 2,052
    int*   bucketCur  = (int*)     (ws + 51859460);   // 2,048
    int*   offs       = (int*)     (ws + 51861508);   // 400,004
    int*   csr        = (int*)     (ws + 52261512);   // 6,400,000 (end 58,661,512)

    // zero: bnst + pooled + bucketCnt (contiguous: 51,200,000 .. 51,857,408)
    const int zwords = (51857408 - 51200000) / 4;     // 164,352
    zero_kernel<<<(zwords + 255) / 256, 256, 0, stream>>>((int*)bnst, zwords);

    bucket_count<<<(N_EDGES + 4095) / 4096, 256, 0, stream>>>(dst, bucketCnt);
    bucket_scan<<<1, 512, 0, stream>>>(bucketCnt, bucketOffs, bucketCur);
    binned_scatter<<<(N_EDGES + CHUNK - 1) / CHUNK, 256, 0, stream>>>(src, dst, bucketCur, pairs);
    csr_finalize<<<NBUSED, 256, 0, stream>>>(pairs, bucketOffs, offs, csr);

    for (int l = 0; l < N_CONV; l++) {
        float* bn1p = bnst + (long)l * 8192;
        float* bn2p = bn1p + 4096;
        float* pl = pooled + (long)l * N_GRAPHS * 64;
        if (l == 0)
            gemm_fc1_f32<<<3125, 256, 0, stream>>>(h, fc1w0, X16);
        else
            gemm_fc1_bf16<<<1563, 256, 0, stream>>>(H16, fc1w + (long)(l - 1) * 4096, X16);
        aggregate<<<3125, 256, 0, stream>>>(X16, offs, csr, A_f32, bn1p);
        gemm_fc2<<<1563, 256, 0, stream>>>(A_f32, fc2w + (long)l * 4096, bn1p,
                                           bn1g + l * 64, bn1b + l * 64, X16, bn2p);
        bn_relu_pool<<<391, 256, 0, stream>>>(X16, bn2p, bn2g + l * 64, bn2b + l * 64,
                                              gid, H16, pl);
    }
    score_kernel<<<64, 256, 0, stream>>>(pooled, pw, pb, out);
}

// Round 5
// 618.177 us; speedup vs baseline: 1.7643x; 1.1214x over previous
//
#include <hip/hip_runtime.h>

#define N_NODES 100000
#define N_EDGES 1600000
#define N_GRAPHS 512
#define D_IN 128
#define D_H 64
#define D_OUT 32
#define N_CONV 4
#define BN_EPS 1e-5f
#define NSLOT 32

#define NB 512        // buckets
#define NPB 196       // nodes per bucket
#define NBUSED 511
#define CHUNK 8192    // edges per binned_scatter block
#define MAXE 4096     // max edges per bucket (mean 3136)

typedef unsigned short ushort_t;
typedef unsigned int uint_t;

__device__ inline float b2f(ushort_t u) {
    union { uint_t i; float f; } c; c.i = ((uint_t)u) << 16; return c.f;
}
__device__ inline ushort_t f2b(float f) {
    union { uint_t i; float f; } c; c.f = f;
    uint_t r = (c.i + 0x7fffu + ((c.i >> 16) & 1u)) >> 16;
    return (ushort_t)r;
}
__device__ inline float blo(uint_t v) { return b2f((ushort_t)(v & 0xffffu)); }
__device__ inline float bhi(uint_t v) { return b2f((ushort_t)(v >> 16)); }

// ---------------- utility: zero a region ------------------------------------
__global__ __launch_bounds__(256) void zero_kernel(int* __restrict__ p, int nwords) {
    int i = blockIdx.x * 256 + threadIdx.x;
    if (i < nwords) p[i] = 0;
}

// ---------------- CSR build: bucket histogram -------------------------------
__global__ __launch_bounds__(256) void bucket_count(const int* __restrict__ dst,
                                                    int* __restrict__ bucketCnt) {
    __shared__ int l[NB];
    int t = threadIdx.x;
    for (int i = t; i < NB; i += 256) l[i] = 0;
    __syncthreads();
    long base = (long)blockIdx.x * 4096;
    for (int i = t; i < 4096; i += 256) {
        long e = base + i;
        if (e < N_EDGES) atomicAdd(&l[(unsigned)dst[e] / NPB], 1);
    }
    __syncthreads();
    for (int i = t; i < NB; i += 256) if (l[i]) atomicAdd(&bucketCnt[i], l[i]);
}

// ---------------- bucket offsets scan ---------------------------------------
__global__ __launch_bounds__(512) void bucket_scan(const int* __restrict__ bucketCnt,
                                                   int* __restrict__ bucketOffs,
                                                   int* __restrict__ bucketCur) {
    __shared__ int s[512];
    int t = threadIdx.x;
    int v = bucketCnt[t];
    s[t] = v;
    __syncthreads();
    for (int off = 1; off < 512; off <<= 1) {
        int u = (t >= off) ? s[t - off] : 0;
        __syncthreads();
        s[t] += u;
        __syncthreads();
    }
    int excl = s[t] - v;
    bucketOffs[t] = excl;
    bucketCur[t] = excl;
    if (t == 511) bucketOffs[512] = s[511];
}

// ---------------- binned scatter: LDS counting-sort by bucket ----------------
__global__ __launch_bounds__(256) void binned_scatter(const int* __restrict__ src,
                                                      const int* __restrict__ dst,
                                                      int* __restrict__ bucketCur,
                                                      uint2* __restrict__ pairs) {
    __shared__ uint2 sorted[CHUNK];          // 64 KB
    __shared__ int lcnt[NB], loffs[NB], lcur[NB], gbase[NB];
    __shared__ int ps[256];
    int t = threadIdx.x;
    long e0 = (long)blockIdx.x * CHUNK;
    int nvalid = (int)min((long)CHUNK, (long)N_EDGES - e0);
    for (int i = t; i < NB; i += 256) lcnt[i] = 0;
    __syncthreads();
    for (int i = t; i < nvalid; i += 256)
        atomicAdd(&lcnt[(unsigned)dst[e0 + i] / NPB], 1);
    __syncthreads();
    int a0 = lcnt[2 * t], a1 = lcnt[2 * t + 1];
    ps[t] = a0 + a1;
    __syncthreads();
    for (int off = 1; off < 256; off <<= 1) {
        int u = (t >= off) ? ps[t - off] : 0;
        __syncthreads();
        ps[t] += u;
        __syncthreads();
    }
    int ex = ps[t] - (a0 + a1);
    loffs[2 * t] = ex; loffs[2 * t + 1] = ex + a0;
    lcur[2 * t] = ex;  lcur[2 * t + 1] = ex + a0;
    __syncthreads();
    for (int i = t; i < NB; i += 256) {
        int c = lcnt[i];
        gbase[i] = c ? atomicAdd(&bucketCur[i], c) : 0;
    }
    for (int i = t; i < nvalid; i += 256) {
        int d = dst[e0 + i];
        int b = (unsigned)d / NPB;
        int pos = atomicAdd(&lcur[b], 1);
        sorted[pos] = make_uint2((unsigned)src[e0 + i], (unsigned)d);
    }
    __syncthreads();
    for (int i = t; i < nvalid; i += 256) {
        uint2 pr = sorted[i];
        int b = pr.y / NPB;
        long gpos = (long)gbase[b] + (i - loffs[b]);
        pairs[gpos] = pr;
    }
}

// ---------------- per-bucket CSR finalize -----------------------------------
__global__ __launch_bounds__(256) void csr_finalize(const uint2* __restrict__ pairs,
                                                    const int* __restrict__ bucketOffs,
                                                    int* __restrict__ offs,
                                                    int* __restrict__ csr) {
    __shared__ uint2 lp[MAXE];     // 32 KB
    __shared__ int lsrc[MAXE];     // 16 KB
    __shared__ int lcnt[NPB], lofs[NPB + 1], lcur[NPB];
    __shared__ int ls[256];
    int b = blockIdx.x, t = threadIdx.x;
    int e0 = bucketOffs[b], e1 = bucketOffs[b + 1];
    int ne = e1 - e0;
    int n0 = b * NPB;
    int nn = min(NPB, N_NODES - n0);
    for (int i = t; i < ne; i += 256) lp[i] = pairs[e0 + i];
    for (int i = t; i < nn; i += 256) lcnt[i] = 0;
    __syncthreads();
    for (int i = t; i < ne; i += 256) atomicAdd(&lcnt[lp[i].y - n0], 1);
    __syncthreads();
    int v = (t < nn) ? lcnt[t] : 0;
    ls[t] = v;
    __syncthreads();
    for (int off = 1; off < 256; off <<= 1) {
        int u = (t >= off) ? ls[t - off] : 0;
        __syncthreads();
        ls[t] += u;
        __syncthreads();
    }
    if (t < nn) { lofs[t] = ls[t] - v; lcur[t] = ls[t] - v; offs[n0 + t] = e0 + ls[t] - v; }
    if (t == 0 && b == NBUSED - 1) offs[N_NODES] = e1;
    __syncthreads();
    for (int i = t; i < ne; i += 256) {
        int pos = atomicAdd(&lcur[lp[i].y - n0], 1);
        lsrc[pos] = (int)lp[i].x;
    }
    __syncthreads();
    for (int i = t; i < ne; i += 256) csr[e0 + i] = lsrc[i];
}

// ------------- GEMM layer0: y16 = h(f32, N x 128) @ w -> bf16 ---------------
// weights in LDS; input via wave-broadcast global loads; 64 rows/block
__global__ __launch_bounds__(256) void gemm_fc1_f32(const float* __restrict__ in,
                                                    const float* __restrict__ w,
                                                    ushort_t* __restrict__ y16) {
    __shared__ float lw[128][64];   // 32 KB
    int t = threadIdx.x;
    for (int i = t; i < 128 * 64; i += 256) lw[i >> 6][i & 63] = w[i];
    __syncthreads();
    int cg = t & 15, rg = t >> 4;
    long base = (long)blockIdx.x * 64 + rg * 4;
    const float* r0 = in + min(base + 0, (long)N_NODES - 1) * 128;
    const float* r1 = in + min(base + 1, (long)N_NODES - 1) * 128;
    const float* r2 = in + min(base + 2, (long)N_NODES - 1) * 128;
    const float* r3 = in + min(base + 3, (long)N_NODES - 1) * 128;
    float4 a0, a1, a2, a3;
    a0 = a1 = a2 = a3 = make_float4(0.f, 0.f, 0.f, 0.f);
#pragma unroll 4
    for (int k = 0; k < 128; k++) {
        float4 wv = *(const float4*)&lw[k][cg * 4];
        float v0 = r0[k], v1 = r1[k], v2 = r2[k], v3 = r3[k];
        a0.x += v0 * wv.x; a0.y += v0 * wv.y; a0.z += v0 * wv.z; a0.w += v0 * wv.w;
        a1.x += v1 * wv.x; a1.y += v1 * wv.y; a1.z += v1 * wv.z; a1.w += v1 * wv.w;
        a2.x += v2 * wv.x; a2.y += v2 * wv.y; a2.z += v2 * wv.z; a2.w += v2 * wv.w;
        a3.x += v3 * wv.x; a3.y += v3 * wv.y; a3.z += v3 * wv.z; a3.w += v3 * wv.w;
    }
    float4 aa[4] = {a0, a1, a2, a3};
#pragma unroll
    for (int j = 0; j < 4; j++) {
        long n = base + j;
        if (n < N_NODES) {
            uint2 o;
            o.x = (uint_t)f2b(aa[j].x) | ((uint_t)f2b(aa[j].y) << 16);
            o.y = (uint_t)f2b(aa[j].z) | ((uint_t)f2b(aa[j].w) << 16);
            *(uint2*)&y16[n * 64 + cg * 4] = o;
        }
    }
}

// --- GEMM layers 1+: y16 = relu(BN2(h2_bf16)) @ w -> bf16 (BN fused) --------
__global__ __launch_bounds__(256) void gemm_fc1_bf16(const uint_t* __restrict__ h2,
                                                     const float* __restrict__ w,
                                                     const float* __restrict__ bn2p,
                                                     const float* __restrict__ g2,
                                                     const float* __restrict__ b2,
                                                     ushort_t* __restrict__ y16) {
    __shared__ float lw[64][64];    // 16 KB
    __shared__ float sc[64], sh[64];
    int t = threadIdx.x;
    if (t < 64) {
        float S = 0.f, S2 = 0.f;
        for (int s = 0; s < NSLOT; s++) { S += bn2p[s * 128 + t]; S2 += bn2p[s * 128 + 64 + t]; }
        float mean = S * (1.f / N_NODES);
        float var = S2 * (1.f / N_NODES) - mean * mean;
        float r = rsqrtf(var + BN_EPS);
        float scv = g2[t] * r;
        sc[t] = scv; sh[t] = b2[t] - mean * scv;
    }
    for (int i = t; i < 4096; i += 256) lw[i >> 6][i & 63] = w[i];
    __syncthreads();
    int cg = t & 15, rg = t >> 4;
    long base = (long)blockIdx.x * 64 + rg * 4;
    const uint_t* r0 = h2 + min(base + 0, (long)N_NODES - 1) * 32;
    const uint_t* r1 = h2 + min(base + 1, (long)N_NODES - 1) * 32;
    const uint_t* r2 = h2 + min(base + 2, (long)N_NODES - 1) * 32;
    const uint_t* r3 = h2 + min(base + 3, (long)N_NODES - 1) * 32;
    float4 a0, a1, a2, a3;
    a0 = a1 = a2 = a3 = make_float4(0.f, 0.f, 0.f, 0.f);
#pragma unroll 4
    for (int kp = 0; kp < 32; kp++) {
        uint_t u0 = r0[kp], u1 = r1[kp], u2 = r2[kp], u3 = r3[kp];
        float sA = sc[2 * kp], hA = sh[2 * kp];
        float sB = sc[2 * kp + 1], hB = sh[2 * kp + 1];
        float4 w0 = *(const float4*)&lw[2 * kp][cg * 4];
        float4 w1 = *(const float4*)&lw[2 * kp + 1][cg * 4];
        float x0a = fmaxf(blo(u0) * sA + hA, 0.f), x0b = fmaxf(bhi(u0) * sB + hB, 0.f);
        float x1a = fmaxf(blo(u1) * sA + hA, 0.f), x1b = fmaxf(bhi(u1) * sB + hB, 0.f);
        float x2a = fmaxf(blo(u2) * sA + hA, 0.f), x2b = fmaxf(bhi(u2) * sB + hB, 0.f);
        float x3a = fmaxf(blo(u3) * sA + hA, 0.f), x3b = fmaxf(bhi(u3) * sB + hB, 0.f);
        a0.x += x0a * w0.x + x0b * w1.x; a0.y += x0a * w0.y + x0b * w1.y;
        a0.z += x0a * w0.z + x0b * w1.z; a0.w += x0a * w0.w + x0b * w1.w;
        a1.x += x1a * w0.x + x1b * w1.x; a1.y += x1a * w0.y + x1b * w1.y;
        a1.z += x1a * w0.z + x1b * w1.z; a1.w += x1a * w0.w + x1b * w1.w;
        a2.x += x2a * w0.x + x2b * w1.x; a2.y += x2a * w0.y + x2b * w1.y;
        a2.z += x2a * w0.z + x2b * w1.z; a2.w += x2a * w0.w + x2b * w1.w;
        a3.x += x3a * w0.x + x3b * w1.x; a3.y += x3a * w0.y + x3b * w1.y;
        a3.z += x3a * w0.z + x3b * w1.z; a3.w += x3a * w0.w + x3b * w1.w;
    }
    float4 aa[4] = {a0, a1, a2, a3};
#pragma unroll
    for (int j = 0; j < 4; j++) {
        long n = base + j;
        if (n < N_NODES) {
            uint2 o;
            o.x = (uint_t)f2b(aa[j].x) | ((uint_t)f2b(aa[j].y) << 16);
            o.y = (uint_t)f2b(aa[j].z) | ((uint_t)f2b(aa[j].w) << 16);
            *(uint2*)&y16[n * 64 + cg * 4] = o;
        }
    }
}

// ------- aggregation: agg(f32) = y16 + sum_nb y16[nb] + BN1 stats -----------
// lane = (col-pair c, half); halves split edge list; 4B loads
__global__ __launch_bounds__(256) void aggregate(const uint_t* __restrict__ y32,
                                                 const int* __restrict__ offs,
                                                 const int* __restrict__ csr,
                                                 float* __restrict__ agg,
                                                 float* __restrict__ bn1p) {
    int t = threadIdx.x;
    int wv = t >> 6, lane = t & 63;
    int c = lane & 31, half = lane >> 5;
    float s1a = 0.f, s2a = 0.f, s1b = 0.f, s2b = 0.f;
    int nb_base = blockIdx.x * 32 + wv * 8;
    __shared__ float l1[4][64], l2[4][64];
    for (int j = 0; j < 8; j++) {
        int n = nb_base + j;
        if (n >= N_NODES) break;
        float sum0 = 0.f, sum1 = 0.f;
        if (half == 0) {
            uint_t v = y32[(long)n * 32 + c];
            sum0 = blo(v); sum1 = bhi(v);
        }
        int p0 = offs[n], p1 = offs[n + 1];
        int p = p0 + half;
        for (; p + 6 < p1; p += 8) {
            int i0 = csr[p], i1 = csr[p + 2], i2 = csr[p + 4], i3 = csr[p + 6];
            uint_t v0 = y32[(long)i0 * 32 + c];
            uint_t v1 = y32[(long)i1 * 32 + c];
            uint_t v2 = y32[(long)i2 * 32 + c];
            uint_t v3 = y32[(long)i3 * 32 + c];
            sum0 += (blo(v0) + blo(v1)) + (blo(v2) + blo(v3));
            sum1 += (bhi(v0) + bhi(v1)) + (bhi(v2) + bhi(v3));
        }
        for (; p < p1; p += 2) {
            uint_t v = y32[(long)csr[p] * 32 + c];
            sum0 += blo(v); sum1 += bhi(v);
        }
        sum0 += __shfl_xor(sum0, 32);
        sum1 += __shfl_xor(sum1, 32);
        if (half == 0) {
            *(float2*)&agg[(long)n * 64 + 2 * c] = make_float2(sum0, sum1);
            s1a += sum0; s2a += sum0 * sum0;
            s1b += sum1; s2b += sum1 * sum1;
        }
    }
    if (half == 0) {
        l1[wv][2 * c] = s1a; l1[wv][2 * c + 1] = s1b;
        l2[wv][2 * c] = s2a; l2[wv][2 * c + 1] = s2b;
    }
    __syncthreads();
    if (t < 64) {
        float S = l1[0][t] + l1[1][t] + l1[2][t] + l1[3][t];
        float S2 = l2[0][t] + l2[1][t] + l2[2][t] + l2[3][t];
        int slot = blockIdx.x & (NSLOT - 1);
        atomicAdd(&bn1p[slot * 128 + t], S);
        atomicAdd(&bn1p[slot * 128 + 64 + t], S2);
    }
}

// --------- h2(bf16) = relu(BN1(agg)) @ fc2, accumulating BN2 stats ----------
__global__ __launch_bounds__(256) void gemm_fc2(const float* __restrict__ agg,
                                                const float* __restrict__ w,
                                                const float* __restrict__ bn1p,
                                                const float* __restrict__ g1,
                                                const float* __restrict__ b1,
                                                ushort_t* __restrict__ h2,
                                                float* __restrict__ bn2p) {
    __shared__ float lw[64][64];            // 16 KB
    __shared__ float sc[64], sh[64];
    __shared__ float red1[16][64], red2[16][64];  // 8 KB
    int t = threadIdx.x;
    if (t < 64) {
        float S = 0.f, S2 = 0.f;
        for (int s = 0; s < NSLOT; s++) { S += bn1p[s * 128 + t]; S2 += bn1p[s * 128 + 64 + t]; }
        float mean = S * (1.f / N_NODES);
        float var = S2 * (1.f / N_NODES) - mean * mean;
        float r = rsqrtf(var + BN_EPS);
        float scv = g1[t] * r;
        sc[t] = scv; sh[t] = b1[t] - mean * scv;
    }
    for (int i = t; i < 4096; i += 256) lw[i >> 6][i & 63] = w[i];
    __syncthreads();
    int cg = t & 15, rg = t >> 4;
    long base = (long)blockIdx.x * 64 + rg * 4;
    const float* r0 = agg + min(base + 0, (long)N_NODES - 1) * 64;
    const float* r1 = agg + min(base + 1, (long)N_NODES - 1) * 64;
    const float* r2 = agg + min(base + 2, (long)N_NODES - 1) * 64;
    const float* r3 = agg + min(base + 3, (long)N_NODES - 1) * 64;
    float4 a0, a1, a2, a3;
    a0 = a1 = a2 = a3 = make_float4(0.f, 0.f, 0.f, 0.f);
#pragma unroll 4
    for (int k = 0; k < 64; k++) {
        float sck = sc[k], shk = sh[k];
        float4 wv = *(const float4*)&lw[k][cg * 4];
        float v0 = fmaxf(r0[k] * sck + shk, 0.f);
        float v1 = fmaxf(r1[k] * sck + shk, 0.f);
        float v2 = fmaxf(r2[k] * sck + shk, 0.f);
        float v3 = fmaxf(r3[k] * sck + shk, 0.f);
        a0.x += v0 * wv.x; a0.y += v0 * wv.y; a0.z += v0 * wv.z; a0.w += v0 * wv.w;
        a1.x += v1 * wv.x; a1.y += v1 * wv.y; a1.z += v1 * wv.z; a1.w += v1 * wv.w;
        a2.x += v2 * wv.x; a2.y += v2 * wv.y; a2.z += v2 * wv.z; a2.w += v2 * wv.w;
        a3.x += v3 * wv.x; a3.y += v3 * wv.y; a3.z += v3 * wv.z; a3.w += v3 * wv.w;
    }
    float4 aa[4] = {a0, a1, a2, a3};
    float s1[4] = {0.f, 0.f, 0.f, 0.f}, s2[4] = {0.f, 0.f, 0.f, 0.f};
#pragma unroll
    for (int j = 0; j < 4; j++) {
        long n = base + j;
        if (n < N_NODES) {
            uint2 o;
            o.x = (uint_t)f2b(aa[j].x) | ((uint_t)f2b(aa[j].y) << 16);
            o.y = (uint_t)f2b(aa[j].z) | ((uint_t)f2b(aa[j].w) << 16);
            *(uint2*)&h2[n * 64 + cg * 4] = o;
            float* a = (float*)&aa[j];
#pragma unroll
            for (int m = 0; m < 4; m++) { s1[m] += a[m]; s2[m] += a[m] * a[m]; }
        }
    }
#pragma unroll
    for (int m = 0; m < 4; m++) {
        red1[rg][cg * 4 + m] = s1[m];
        red2[rg][cg * 4 + m] = s2[m];
    }
    __syncthreads();
    if (t < 64) {
        float S = 0.f, S2 = 0.f;
        for (int gg = 0; gg < 16; gg++) { S += red1[gg][t]; S2 += red2[gg][t]; }
        int slot = blockIdx.x & (NSLOT - 1);
        atomicAdd(&bn2p[slot * 128 + t], S);
        atomicAdd(&bn2p[slot * 128 + 64 + t], S2);
    }
}

// --- pooled[g] += relu(BN2(h2)) (sorted graph_ids); no hnew materialized ----
__global__ __launch_bounds__(256) void bn_pool(const uint_t* __restrict__ h2,
                                               const float* __restrict__ bn2p,
                                               const float* __restrict__ g2,
                                               const float* __restrict__ b2,
                                               const int* __restrict__ gid,
                                               float* __restrict__ pooled) {
    __shared__ float sc[64], sh[64];
    int t = threadIdx.x;
    if (t < 64) {
        float S = 0.f, S2 = 0.f;
        for (int s = 0; s < NSLOT; s++) { S += bn2p[s * 128 + t]; S2 += bn2p[s * 128 + 64 + t]; }
        float mean = S * (1.f / N_NODES);
        float var = S2 * (1.f / N_NODES) - mean * mean;
        float r = rsqrtf(var + BN_EPS);
        float scv = g2[t] * r;
        sc[t] = scv; sh[t] = b2[t] - mean * scv;
    }
    __syncthreads();
    int c = t & 31, rs = t >> 5;
    float sA = sc[2 * c], hA = sh[2 * c], sB = sc[2 * c + 1], hB = sh[2 * c + 1];
    long base = (long)blockIdx.x * 256;
    float pa = 0.f, pb2 = 0.f; int gc = -1;
    for (int i = 0; i < 32; i++) {
        long n = base + rs + 8 * i;
        if (n >= N_NODES) break;
        int g = gid[n];
        uint_t v = h2[n * 32 + c];
        float x0 = fmaxf(blo(v) * sA + hA, 0.f);
        float x1 = fmaxf(bhi(v) * sB + hB, 0.f);
        if (g != gc) {
            if (gc >= 0) {
                atomicAdd(&pooled[(long)gc * 64 + 2 * c], pa);
                atomicAdd(&pooled[(long)gc * 64 + 2 * c + 1], pb2);
            }
            gc = g; pa = 0.f; pb2 = 0.f;
        }
        pa += x0; pb2 += x1;
    }
    if (gc >= 0) {
        atomicAdd(&pooled[(long)gc * 64 + 2 * c], pa);
        atomicAdd(&pooled[(long)gc * 64 + 2 * c + 1], pb2);
    }
}

// --------- score = sum_l pooled_l @ pred_w_l + pred_b_l --------------------
__global__ __launch_bounds__(256) void score_kernel(const float* __restrict__ pooled,
                                                    const float* __restrict__ pw,
                                                    const float* __restrict__ pb,
                                                    float* __restrict__ out) {
    int idx = blockIdx.x * 256 + threadIdx.x;  // 16384 = 512*32
    int g = idx >> 5, o = idx & 31;
    float acc = 0.f;
    for (int l = 0; l < N_CONV; l++) {
        acc += pb[l * 32 + o];
        const float* pr = pooled + (long)l * N_GRAPHS * 64 + (long)g * 64;
        const float* wr = pw + l * 64 * 32;
        for (int k = 0; k < 64; k++) acc += pr[k] * wr[k * 32 + o];
    }
    out[idx] = acc;
}

extern "C" void kernel_launch(void* const* d_in, const int* in_sizes, int n_in,
                              void* d_out, int out_size, void* d_ws, size_t ws_size,
                              hipStream_t stream) {
    const float* h     = (const float*)d_in[0];
    const int*   src   = (const int*)d_in[1];
    const int*   dst   = (const int*)d_in[2];
    const int*   gid   = (const int*)d_in[3];
    const float* fc1w0 = (const float*)d_in[4];
    const float* fc1w  = (const float*)d_in[5];
    const float* fc2w  = (const float*)d_in[6];
    const float* bn1g  = (const float*)d_in[7];
    const float* bn1b  = (const float*)d_in[8];
    const float* bn2g  = (const float*)d_in[9];
    const float* bn2b  = (const float*)d_in[10];
    const float* pw    = (const float*)d_in[11];
    const float* pb    = (const float*)d_in[12];
    float* out = (float*)d_out;

    char* ws = (char*)d_ws;
    float*    A_f32   = (float*)   (ws);              // agg f32: 25,600,000
    uint2*    pairs   = (uint2*)   (ws);              // 12,800,000 (aliases A_f32; dead before layer-0 aggregate)
    ushort_t* X16     = (ushort_t*)(ws + 25600000);   // h2 bf16: 12,800,000
    ushort_t* Y16     = (ushort_t*)(ws + 38400000);   // y bf16: 12,800,000
    float*    bnst    = (float*)   (ws + 51200000);   // 131,072
    float*    pooled  = (float*)   (ws + 51331072);   // 524,288
    int*   bucketCnt  = (int*)     (ws + 51855360);   // 2,048
    int*   bucketOffs = (int*)     (ws + 51857408);   // 2,052
    int*   bucketCur  = (int*)     (ws + 51859460);   // 2,048
    int*   offs       = (int*)     (ws + 51861508);   // 400,004
    int*   csr        = (int*)     (ws + 52261512);   // 6,400,000 (end 58,661,512)

    // zero: bnst + pooled + bucketCnt (contiguous: 51,200,000 .. 51,857,408)
    const int zwords = (51857408 - 51200000) / 4;     // 164,352
    zero_kernel<<<(zwords + 255) / 256, 256, 0, stream>>>((int*)bnst, zwords);

    bucket_count<<<(N_EDGES + 4095) / 4096, 256, 0, stream>>>(dst, bucketCnt);
    bucket_scan<<<1, 512, 0, stream>>>(bucketCnt, bucketOffs, bucketCur);
    binned_scatter<<<(N_EDGES + CHUNK - 1) / CHUNK, 256, 0, stream>>>(src, dst, bucketCur, pairs);
    csr_finalize<<<NBUSED, 256, 0, stream>>>(pairs, bucketOffs, offs, csr);

    const int GEMM_GRID = (N_NODES + 63) / 64;  // 1563
    for (int l = 0; l < N_CONV; l++) {
        float* bn1p = bnst + (long)l * 8192;
        float* bn2p = bn1p + 4096;
        float* pl = pooled + (long)l * N_GRAPHS * 64;
        if (l == 0) {
            gemm_fc1_f32<<<GEMM_GRID, 256, 0, stream>>>(h, fc1w0, Y16);
        } else {
            float* bn2p_prev = bnst + (long)(l - 1) * 8192 + 4096;
            gemm_fc1_bf16<<<GEMM_GRID, 256, 0, stream>>>((const uint_t*)X16,
                fc1w + (long)(l - 1) * 4096, bn2p_prev,
                bn2g + (l - 1) * 64, bn2b + (l - 1) * 64, Y16);
        }
        aggregate<<<3125, 256, 0, stream>>>((const uint_t*)Y16, offs, csr, A_f32, bn1p);
        gemm_fc2<<<GEMM_GRID, 256, 0, stream>>>(A_f32, fc2w + (long)l * 4096, bn1p,
                                                bn1g + l * 64, bn1b + l * 64, X16, bn2p);
        bn_pool<<<391, 256, 0, stream>>>((const uint_t*)X16, bn2p, bn2g + l * 64,
                                         bn2b + l * 64, gid, pl);
    }
    score_kernel<<<64, 256, 0, stream>>>(pooled, pw, pb, out);
}

// Round 6
// 547.107 us; speedup vs baseline: 1.9935x; 1.1299x over previous
//
#include <hip/hip_runtime.h>

#define N_NODES 100000
#define N_EDGES 1600000
#define N_GRAPHS 512
#define D_IN 128
#define D_H 64
#define D_OUT 32
#define N_CONV 4
#define BN_EPS 1e-5f
#define NSLOT 32

#define NB 512        // buckets
#define NPB 196       // nodes per bucket
#define NBUSED 511
#define CHUNK 8192    // edges per binned_scatter block
#define MAXE 4096     // max edges per bucket (mean 3136)

typedef unsigned short ushort_t;
typedef unsigned int uint_t;

__device__ inline float b2f(ushort_t u) {
    union { uint_t i; float f; } c; c.i = ((uint_t)u) << 16; return c.f;
}
__device__ inline ushort_t f2b(float f) {
    union { uint_t i; float f; } c; c.f = f;
    uint_t r = (c.i + 0x7fffu + ((c.i >> 16) & 1u)) >> 16;
    return (ushort_t)r;
}
__device__ inline float blo(uint_t v) { return b2f((ushort_t)(v & 0xffffu)); }
__device__ inline float bhi(uint_t v) { return b2f((ushort_t)(v >> 16)); }

// ---------------- utility: zero a region ------------------------------------
__global__ __launch_bounds__(256) void zero_kernel(int* __restrict__ p, int nwords) {
    int i = blockIdx.x * 256 + threadIdx.x;
    if (i < nwords) p[i] = 0;
}

// ---------------- CSR build: bucket histogram -------------------------------
__global__ __launch_bounds__(256) void bucket_count(const int* __restrict__ dst,
                                                    int* __restrict__ bucketCnt) {
    __shared__ int l[NB];
    int t = threadIdx.x;
    for (int i = t; i < NB; i += 256) l[i] = 0;
    __syncthreads();
    long base = (long)blockIdx.x * 4096;
    for (int i = t; i < 4096; i += 256) {
        long e = base + i;
        if (e < N_EDGES) atomicAdd(&l[(unsigned)dst[e] / NPB], 1);
    }
    __syncthreads();
    for (int i = t; i < NB; i += 256) if (l[i]) atomicAdd(&bucketCnt[i], l[i]);
}

// ---------------- bucket offsets scan ---------------------------------------
__global__ __launch_bounds__(512) void bucket_scan(const int* __restrict__ bucketCnt,
                                                   int* __restrict__ bucketOffs,
                                                   int* __restrict__ bucketCur) {
    __shared__ int s[512];
    int t = threadIdx.x;
    int v = bucketCnt[t];
    s[t] = v;
    __syncthreads();
    for (int off = 1; off < 512; off <<= 1) {
        int u = (t >= off) ? s[t - off] : 0;
        __syncthreads();
        s[t] += u;
        __syncthreads();
    }
    int excl = s[t] - v;
    bucketOffs[t] = excl;
    bucketCur[t] = excl;
    if (t == 511) bucketOffs[512] = s[511];
}

// ---------------- binned scatter: LDS counting-sort by bucket ----------------
__global__ __launch_bounds__(256) void binned_scatter(const int* __restrict__ src,
                                                      const int* __restrict__ dst,
                                                      int* __restrict__ bucketCur,
                                                      uint2* __restrict__ pairs) {
    __shared__ uint2 sorted[CHUNK];          // 64 KB
    __shared__ int lcnt[NB], loffs[NB], lcur[NB], gbase[NB];
    __shared__ int ps[256];
    int t = threadIdx.x;
    long e0 = (long)blockIdx.x * CHUNK;
    int nvalid = (int)min((long)CHUNK, (long)N_EDGES - e0);
    for (int i = t; i < NB; i += 256) lcnt[i] = 0;
    __syncthreads();
    for (int i = t; i < nvalid; i += 256)
        atomicAdd(&lcnt[(unsigned)dst[e0 + i] / NPB], 1);
    __syncthreads();
    int a0 = lcnt[2 * t], a1 = lcnt[2 * t + 1];
    ps[t] = a0 + a1;
    __syncthreads();
    for (int off = 1; off < 256; off <<= 1) {
        int u = (t >= off) ? ps[t - off] : 0;
        __syncthreads();
        ps[t] += u;
        __syncthreads();
    }
    int ex = ps[t] - (a0 + a1);
    loffs[2 * t] = ex; loffs[2 * t + 1] = ex + a0;
    lcur[2 * t] = ex;  lcur[2 * t + 1] = ex + a0;
    __syncthreads();
    for (int i = t; i < NB; i += 256) {
        int c = lcnt[i];
        gbase[i] = c ? atomicAdd(&bucketCur[i], c) : 0;
    }
    for (int i = t; i < nvalid; i += 256) {
        int d = dst[e0 + i];
        int b = (unsigned)d / NPB;
        int pos = atomicAdd(&lcur[b], 1);
        sorted[pos] = make_uint2((unsigned)src[e0 + i], (unsigned)d);
    }
    __syncthreads();
    for (int i = t; i < nvalid; i += 256) {
        uint2 pr = sorted[i];
        int b = pr.y / NPB;
        long gpos = (long)gbase[b] + (i - loffs[b]);
        pairs[gpos] = pr;
    }
}

// ---------------- per-bucket CSR finalize -----------------------------------
__global__ __launch_bounds__(256) void csr_finalize(const uint2* __restrict__ pairs,
                                                    const int* __restrict__ bucketOffs,
                                                    int* __restrict__ offs,
                                                    int* __restrict__ csr) {
    __shared__ uint2 lp[MAXE];     // 32 KB
    __shared__ int lsrc[MAXE];     // 16 KB
    __shared__ int lcnt[NPB], lofs[NPB + 1], lcur[NPB];
    __shared__ int ls[256];
    int b = blockIdx.x, t = threadIdx.x;
    int e0 = bucketOffs[b], e1 = bucketOffs[b + 1];
    int ne = e1 - e0;
    int n0 = b * NPB;
    int nn = min(NPB, N_NODES - n0);
    for (int i = t; i < ne; i += 256) lp[i] = pairs[e0 + i];
    for (int i = t; i < nn; i += 256) lcnt[i] = 0;
    __syncthreads();
    for (int i = t; i < ne; i += 256) atomicAdd(&lcnt[lp[i].y - n0], 1);
    __syncthreads();
    int v = (t < nn) ? lcnt[t] : 0;
    ls[t] = v;
    __syncthreads();
    for (int off = 1; off < 256; off <<= 1) {
        int u = (t >= off) ? ls[t - off] : 0;
        __syncthreads();
        ls[t] += u;
        __syncthreads();
    }
    if (t < nn) { lofs[t] = ls[t] - v; lcur[t] = ls[t] - v; offs[n0 + t] = e0 + ls[t] - v; }
    if (t == 0 && b == NBUSED - 1) offs[N_NODES] = e1;
    __syncthreads();
    for (int i = t; i < ne; i += 256) {
        int pos = atomicAdd(&lcur[lp[i].y - n0], 1);
        lsrc[pos] = (int)lp[i].x;
    }
    __syncthreads();
    for (int i = t; i < ne; i += 256) csr[e0 + i] = lsrc[i];
}

// ------------- GEMM layer0: y16 = h(f32, N x 128) @ w -> bf16 ---------------
__global__ __launch_bounds__(256) void gemm_fc1_f32(const float* __restrict__ in,
                                                    const float* __restrict__ w,
                                                    ushort_t* __restrict__ y16) {
    __shared__ float lw[128][64];   // 32 KB
    int t = threadIdx.x;
    for (int i = t; i < 128 * 64; i += 256) lw[i >> 6][i & 63] = w[i];
    __syncthreads();
    int cg = t & 15, rg = t >> 4;
    long base = (long)blockIdx.x * 64 + rg * 4;
    const float* r0 = in + min(base + 0, (long)N_NODES - 1) * 128;
    const float* r1 = in + min(base + 1, (long)N_NODES - 1) * 128;
    const float* r2 = in + min(base + 2, (long)N_NODES - 1) * 128;
    const float* r3 = in + min(base + 3, (long)N_NODES - 1) * 128;
    float4 a0, a1, a2, a3;
    a0 = a1 = a2 = a3 = make_float4(0.f, 0.f, 0.f, 0.f);
#pragma unroll 4
    for (int k = 0; k < 128; k++) {
        float4 wv = *(const float4*)&lw[k][cg * 4];
        float v0 = r0[k], v1 = r1[k], v2 = r2[k], v3 = r3[k];
        a0.x += v0 * wv.x; a0.y += v0 * wv.y; a0.z += v0 * wv.z; a0.w += v0 * wv.w;
        a1.x += v1 * wv.x; a1.y += v1 * wv.y; a1.z += v1 * wv.z; a1.w += v1 * wv.w;
        a2.x += v2 * wv.x; a2.y += v2 * wv.y; a2.z += v2 * wv.z; a2.w += v2 * wv.w;
        a3.x += v3 * wv.x; a3.y += v3 * wv.y; a3.z += v3 * wv.z; a3.w += v3 * wv.w;
    }
    float4 aa[4] = {a0, a1, a2, a3};
#pragma unroll
    for (int j = 0; j < 4; j++) {
        long n = base + j;
        if (n < N_NODES) {
            uint2 o;
            o.x = (uint_t)f2b(aa[j].x) | ((uint_t)f2b(aa[j].y) << 16);
            o.y = (uint_t)f2b(aa[j].z) | ((uint_t)f2b(aa[j].w) << 16);
            *(uint2*)&y16[n * 64 + cg * 4] = o;
        }
    }
}

// --- GEMM layers 1+: y16 = relu(BN2(h2_bf16)) @ w -> bf16 (BN fused) --------
__global__ __launch_bounds__(256) void gemm_fc1_bf16(const uint_t* __restrict__ h2,
                                                     const float* __restrict__ w,
                                                     const float* __restrict__ bn2p,
                                                     const float* __restrict__ g2,
                                                     const float* __restrict__ b2,
                                                     ushort_t* __restrict__ y16) {
    __shared__ float lw[64][64];    // 16 KB
    __shared__ float sc[64], sh[64];
    int t = threadIdx.x;
    if (t < 64) {
        float S = 0.f, S2 = 0.f;
        for (int s = 0; s < NSLOT; s++) { S += bn2p[s * 128 + t]; S2 += bn2p[s * 128 + 64 + t]; }
        float mean = S * (1.f / N_NODES);
        float var = S2 * (1.f / N_NODES) - mean * mean;
        float r = rsqrtf(var + BN_EPS);
        float scv = g2[t] * r;
        sc[t] = scv; sh[t] = b2[t] - mean * scv;
    }
    for (int i = t; i < 4096; i += 256) lw[i >> 6][i & 63] = w[i];
    __syncthreads();
    int cg = t & 15, rg = t >> 4;
    long base = (long)blockIdx.x * 64 + rg * 4;
    const uint_t* r0 = h2 + min(base + 0, (long)N_NODES - 1) * 32;
    const uint_t* r1 = h2 + min(base + 1, (long)N_NODES - 1) * 32;
    const uint_t* r2 = h2 + min(base + 2, (long)N_NODES - 1) * 32;
    const uint_t* r3 = h2 + min(base + 3, (long)N_NODES - 1) * 32;
    float4 a0, a1, a2, a3;
    a0 = a1 = a2 = a3 = make_float4(0.f, 0.f, 0.f, 0.f);
#pragma unroll 4
    for (int kp = 0; kp < 32; kp++) {
        uint_t u0 = r0[kp], u1 = r1[kp], u2 = r2[kp], u3 = r3[kp];
        float sA = sc[2 * kp], hA = sh[2 * kp];
        float sB = sc[2 * kp + 1], hB = sh[2 * kp + 1];
        float4 w0 = *(const float4*)&lw[2 * kp][cg * 4];
        float4 w1 = *(const float4*)&lw[2 * kp + 1][cg * 4];
        float x0a = fmaxf(blo(u0) * sA + hA, 0.f), x0b = fmaxf(bhi(u0) * sB + hB, 0.f);
        float x1a = fmaxf(blo(u1) * sA + hA, 0.f), x1b = fmaxf(bhi(u1) * sB + hB, 0.f);
        float x2a = fmaxf(blo(u2) * sA + hA, 0.f), x2b = fmaxf(bhi(u2) * sB + hB, 0.f);
        float x3a = fmaxf(blo(u3) * sA + hA, 0.f), x3b = fmaxf(bhi(u3) * sB + hB, 0.f);
        a0.x += x0a * w0.x + x0b * w1.x; a0.y += x0a * w0.y + x0b * w1.y;
        a0.z += x0a * w0.z + x0b * w1.z; a0.w += x0a * w0.w + x0b * w1.w;
        a1.x += x1a * w0.x + x1b * w1.x; a1.y += x1a * w0.y + x1b * w1.y;
        a1.z += x1a * w0.z + x1b * w1.z; a1.w += x1a * w0.w + x1b * w1.w;
        a2.x += x2a * w0.x + x2b * w1.x; a2.y += x2a * w0.y + x2b * w1.y;
        a2.z += x2a * w0.z + x2b * w1.z; a2.w += x2a * w0.w + x2b * w1.w;
        a3.x += x3a * w0.x + x3b * w1.x; a3.y += x3a * w0.y + x3b * w1.y;
        a3.z += x3a * w0.z + x3b * w1.z; a3.w += x3a * w0.w + x3b * w1.w;
    }
    float4 aa[4] = {a0, a1, a2, a3};
#pragma unroll
    for (int j = 0; j < 4; j++) {
        long n = base + j;
        if (n < N_NODES) {
            uint2 o;
            o.x = (uint_t)f2b(aa[j].x) | ((uint_t)f2b(aa[j].y) << 16);
            o.y = (uint_t)f2b(aa[j].z) | ((uint_t)f2b(aa[j].w) << 16);
            *(uint2*)&y16[n * 64 + cg * 4] = o;
        }
    }
}

// ------- aggregation: agg(f32) = y16 + sum_nb y16[nb] + BN1 stats -----------
// lane = (edge-slot g = lane>>3, col-chunk l = lane&7); 16B dwordx4 gathers;
// per-node butterfly reduce over edge slots (shfl_xor 8/16/32)
__global__ __launch_bounds__(256) void aggregate(const uint_t* __restrict__ y32,
                                                 const int* __restrict__ offs,
                                                 const int* __restrict__ csr,
                                                 float* __restrict__ agg,
                                                 float* __restrict__ bn1p) {
    int t = threadIdx.x;
    int wv = t >> 6, lane = t & 63;
    int g = lane >> 3, l = lane & 7;
    __shared__ float l1[4][64], l2[4][64];
    float st1[8], st2[8];
#pragma unroll
    for (int m = 0; m < 8; m++) { st1[m] = 0.f; st2[m] = 0.f; }
    int nb_base = blockIdx.x * 32 + wv * 8;
    for (int j = 0; j < 8; j++) {
        int n = nb_base + j;
        if (n >= N_NODES) break;
        int p0 = offs[n], p1 = offs[n + 1];
        int cnt = 1 + (p1 - p0);            // self + neighbors
        int rounds = (cnt + 7) >> 3;
        float accA[4] = {0.f, 0.f, 0.f, 0.f}, accB[4] = {0.f, 0.f, 0.f, 0.f};
        int e = g;
        int idx = (e == 0) ? n : ((e < cnt) ? csr[p0 + e - 1] : -1);
        for (int r = 0; r < rounds; r++) {
            int ne = e + 8;
            int nidx = (r + 1 < rounds && ne < cnt) ? csr[p0 + ne - 1] : -1;
            if (idx >= 0) {
                uint4 v = *(const uint4*)(y32 + (long)idx * 32 + 4 * l);
                accA[0] += __uint_as_float(v.x << 16);
                accB[0] += __uint_as_float(v.x & 0xffff0000u);
                accA[1] += __uint_as_float(v.y << 16);
                accB[1] += __uint_as_float(v.y & 0xffff0000u);
                accA[2] += __uint_as_float(v.z << 16);
                accB[2] += __uint_as_float(v.z & 0xffff0000u);
                accA[3] += __uint_as_float(v.w << 16);
                accB[3] += __uint_as_float(v.w & 0xffff0000u);
            }
            e = ne; idx = nidx;
        }
#pragma unroll
        for (int m = 0; m < 4; m++) {
            accA[m] += __shfl_xor(accA[m], 8);
            accB[m] += __shfl_xor(accB[m], 8);
            accA[m] += __shfl_xor(accA[m], 16);
            accB[m] += __shfl_xor(accB[m], 16);
            accA[m] += __shfl_xor(accA[m], 32);
            accB[m] += __shfl_xor(accB[m], 32);
        }
        if (g == 0) {
            float4 o0 = make_float4(accA[0], accB[0], accA[1], accB[1]);
            float4 o1 = make_float4(accA[2], accB[2], accA[3], accB[3]);
            *(float4*)&agg[(long)n * 64 + 8 * l] = o0;
            *(float4*)&agg[(long)n * 64 + 8 * l + 4] = o1;
            st1[0] += o0.x; st2[0] += o0.x * o0.x;
            st1[1] += o0.y; st2[1] += o0.y * o0.y;
            st1[2] += o0.z; st2[2] += o0.z * o0.z;
            st1[3] += o0.w; st2[3] += o0.w * o0.w;
            st1[4] += o1.x; st2[4] += o1.x * o1.x;
            st1[5] += o1.y; st2[5] += o1.y * o1.y;
            st1[6] += o1.z; st2[6] += o1.z * o1.z;
            st1[7] += o1.w; st2[7] += o1.w * o1.w;
        }
    }
    if (g == 0) {
#pragma unroll
        for (int m = 0; m < 8; m++) { l1[wv][8 * l + m] = st1[m]; l2[wv][8 * l + m] = st2[m]; }
    }
    __syncthreads();
    if (t < 64) {
        float S = l1[0][t] + l1[1][t] + l1[2][t] + l1[3][t];
        float S2 = l2[0][t] + l2[1][t] + l2[2][t] + l2[3][t];
        int slot = blockIdx.x & (NSLOT - 1);
        atomicAdd(&bn1p[slot * 128 + t], S);
        atomicAdd(&bn1p[slot * 128 + 64 + t], S2);
    }
}

// --------- h2(bf16) = relu(BN1(agg)) @ fc2, accumulating BN2 stats ----------
__global__ __launch_bounds__(256) void gemm_fc2(const float* __restrict__ agg,
                                                const float* __restrict__ w,
                                                const float* __restrict__ bn1p,
                                                const float* __restrict__ g1,
                                                const float* __restrict__ b1,
                                                ushort_t* __restrict__ h2,
                                                float* __restrict__ bn2p) {
    __shared__ float lw[64][64];            // 16 KB
    __shared__ float sc[64], sh[64];
    __shared__ float red1[16][64], red2[16][64];  // 8 KB
    int t = threadIdx.x;
    if (t < 64) {
        float S = 0.f, S2 = 0.f;
        for (int s = 0; s < NSLOT; s++) { S += bn1p[s * 128 + t]; S2 += bn1p[s * 128 + 64 + t]; }
        float mean = S * (1.f / N_NODES);
        float var = S2 * (1.f / N_NODES) - mean * mean;
        float r = rsqrtf(var + BN_EPS);
        float scv = g1[t] * r;
        sc[t] = scv; sh[t] = b1[t] - mean * scv;
    }
    for (int i = t; i < 4096; i += 256) lw[i >> 6][i & 63] = w[i];
    __syncthreads();
    int cg = t & 15, rg = t >> 4;
    long base = (long)blockIdx.x * 64 + rg * 4;
    const float* r0 = agg + min(base + 0, (long)N_NODES - 1) * 64;
    const float* r1 = agg + min(base + 1, (long)N_NODES - 1) * 64;
    const float* r2 = agg + min(base + 2, (long)N_NODES - 1) * 64;
    const float* r3 = agg + min(base + 3, (long)N_NODES - 1) * 64;
    float4 a0, a1, a2, a3;
    a0 = a1 = a2 = a3 = make_float4(0.f, 0.f, 0.f, 0.f);
#pragma unroll 4
    for (int k = 0; k < 64; k++) {
        float sck = sc[k], shk = sh[k];
        float4 wv = *(const float4*)&lw[k][cg * 4];
        float v0 = fmaxf(r0[k] * sck + shk, 0.f);
        float v1 = fmaxf(r1[k] * sck + shk, 0.f);
        float v2 = fmaxf(r2[k] * sck + shk, 0.f);
        float v3 = fmaxf(r3[k] * sck + shk, 0.f);
        a0.x += v0 * wv.x; a0.y += v0 * wv.y; a0.z += v0 * wv.z; a0.w += v0 * wv.w;
        a1.x += v1 * wv.x; a1.y += v1 * wv.y; a1.z += v1 * wv.z; a1.w += v1 * wv.w;
        a2.x += v2 * wv.x; a2.y += v2 * wv.y; a2.z += v2 * wv.z; a2.w += v2 * wv.w;
        a3.x += v3 * wv.x; a3.y += v3 * wv.y; a3.z += v3 * wv.z; a3.w += v3 * wv.w;
    }
    float4 aa[4] = {a0, a1, a2, a3};
    float s1[4] = {0.f, 0.f, 0.f, 0.f}, s2[4] = {0.f, 0.f, 0.f, 0.f};
#pragma unroll
    for (int j = 0; j < 4; j++) {
        long n = base + j;
        if (n < N_NODES) {
            uint2 o;
            o.x = (uint_t)f2b(aa[j].x) | ((uint_t)f2b(aa[j].y) << 16);
            o.y = (uint_t)f2b(aa[j].z) | ((uint_t)f2b(aa[j].w) << 16);
            *(uint2*)&h2[n * 64 + cg * 4] = o;
            float* a = (float*)&aa[j];
#pragma unroll
            for (int m = 0; m < 4; m++) { s1[m] += a[m]; s2[m] += a[m] * a[m]; }
        }
    }
#pragma unroll
    for (int m = 0; m < 4; m++) {
        red1[rg][cg * 4 + m] = s1[m];
        red2[rg][cg * 4 + m] = s2[m];
    }
    __syncthreads();
    if (t < 64) {
        float S = 0.f, S2 = 0.f;
        for (int gg = 0; gg < 16; gg++) { S += red1[gg][t]; S2 += red2[gg][t]; }
        int slot = blockIdx.x & (NSLOT - 1);
        atomicAdd(&bn2p[slot * 128 + t], S);
        atomicAdd(&bn2p[slot * 128 + 64 + t], S2);
    }
}

// --- pooled[g] += relu(BN2(h2)) (sorted graph_ids); no hnew materialized ----
__global__ __launch_bounds__(256) void bn_pool(const uint_t* __restrict__ h2,
                                               const float* __restrict__ bn2p,
                                               const float* __restrict__ g2,
                                               const float* __restrict__ b2,
                                               const int* __restrict__ gid,
                                               float* __restrict__ pooled) {
    __shared__ float sc[64], sh[64];
    int t = threadIdx.x;
    if (t < 64) {
        float S = 0.f, S2 = 0.f;
        for (int s = 0; s < NSLOT; s++) { S += bn2p[s * 128 + t]; S2 += bn2p[s * 128 + 64 + t]; }
        float mean = S * (1.f / N_NODES);
        float var = S2 * (1.f / N_NODES) - mean * mean;
        float r = rsqrtf(var + BN_EPS);
        float scv = g2[t] * r;
        sc[t] = scv; sh[t] = b2[t] - mean * scv;
    }
    __syncthreads();
    int c = t & 31, rs = t >> 5;
    float sA = sc[2 * c], hA = sh[2 * c], sB = sc[2 * c + 1], hB = sh[2 * c + 1];
    long base = (long)blockIdx.x * 256;
    float pa = 0.f, pb2 = 0.f; int gc = -1;
    for (int i = 0; i < 32; i++) {
        long n = base + rs + 8 * i;
        if (n >= N_NODES) break;
        int g = gid[n];
        uint_t v = h2[n * 32 + c];
        float x0 = fmaxf(blo(v) * sA + hA, 0.f);
        float x1 = fmaxf(bhi(v) * sB + hB, 0.f);
        if (g != gc) {
            if (gc >= 0) {
                atomicAdd(&pooled[(long)gc * 64 + 2 * c], pa);
                atomicAdd(&pooled[(long)gc * 64 + 2 * c + 1], pb2);
            }
            gc = g; pa = 0.f; pb2 = 0.f;
        }
        pa += x0; pb2 += x1;
    }
    if (gc >= 0) {
        atomicAdd(&pooled[(long)gc * 64 + 2 * c], pa);
        atomicAdd(&pooled[(long)gc * 64 + 2 * c + 1], pb2);
    }
}

// --------- score = sum_l pooled_l @ pred_w_l + pred_b_l --------------------
__global__ __launch_bounds__(256) void score_kernel(const float* __restrict__ pooled,
                                                    const float* __restrict__ pw,
                                                    const float* __restrict__ pb,
                                                    float* __restrict__ out) {
    int idx = blockIdx.x * 256 + threadIdx.x;  // 16384 = 512*32
    int g = idx >> 5, o = idx & 31;
    float acc = 0.f;
    for (int l = 0; l < N_CONV; l++) {
        acc += pb[l * 32 + o];
        const float* pr = pooled + (long)l * N_GRAPHS * 64 + (long)g * 64;
        const float* wr = pw + l * 64 * 32;
        for (int k = 0; k < 64; k++) acc += pr[k] * wr[k * 32 + o];
    }
    out[idx] = acc;
}

extern "C" void kernel_launch(void* const* d_in, const int* in_sizes, int n_in,
                              void* d_out, int out_size, void* d_ws, size_t ws_size,
                              hipStream_t stream) {
    const float* h     = (const float*)d_in[0];
    const int*   src   = (const int*)d_in[1];
    const int*   dst   = (const int*)d_in[2];
    const int*   gid   = (const int*)d_in[3];
    const float* fc1w0 = (const float*)d_in[4];
    const float* fc1w  = (const float*)d_in[5];
    const float* fc2w  = (const float*)d_in[6];
    const float* bn1g  = (const float*)d_in[7];
    const float* bn1b  = (const float*)d_in[8];
    const float* bn2g  = (const float*)d_in[9];
    const float* bn2b  = (const float*)d_in[10];
    const float* pw    = (const float*)d_in[11];
    const float* pb    = (const float*)d_in[12];
    float* out = (float*)d_out;

    char* ws = (char*)d_ws;
    float*    A_f32   = (float*)   (ws);              // agg f32: 25,600,000
    uint2*    pairs   = (uint2*)   (ws);              // 12,800,000 (aliases A_f32; dead before layer-0 aggregate)
    ushort_t* X16     = (ushort_t*)(ws + 25600000);   // h2 bf16: 12,800,000
    ushort_t* Y16     = (ushort_t*)(ws + 38400000);   // y bf16: 12,800,000
    float*    bnst    = (float*)   (ws + 51200000);   // 131,072
    float*    pooled  = (float*)   (ws + 51331072);   // 524,288
    int*   bucketCnt  = (int*)     (ws + 51855360);   // 2,048
    int*   bucketOffs = (int*)     (ws + 51857408);   // 2,052
    int*   bucketCur  = (int*)     (ws + 51859460);   // 2,048
    int*   offs       = (int*)     (ws + 51861508);   // 400,004
    int*   csr        = (int*)     (ws + 52261512);   // 6,400,000 (end 58,661,512)

    // zero: bnst + pooled + bucketCnt (contiguous: 51,200,000 .. 51,857,408)
    const int zwords = (51857408 - 51200000) / 4;     // 164,352
    zero_kernel<<<(zwords + 255) / 256, 256, 0, stream>>>((int*)bnst, zwords);

    bucket_count<<<(N_EDGES + 4095) / 4096, 256, 0, stream>>>(dst, bucketCnt);
    bucket_scan<<<1, 512, 0, stream>>>(bucketCnt, bucketOffs, bucketCur);
    binned_scatter<<<(N_EDGES + CHUNK - 1) / CHUNK, 256, 0, stream>>>(src, dst, bucketCur, pairs);
    csr_finalize<<<NBUSED, 256, 0, stream>>>(pairs, bucketOffs, offs, csr);

    const int GEMM_GRID = (N_NODES + 63) / 64;  // 1563
    for (int l = 0; l < N_CONV; l++) {
        float* bn1p = bnst + (long)l * 8192;
        float* bn2p = bn1p + 4096;
        float* pl = pooled + (long)l * N_GRAPHS * 64;
        if (l == 0) {
            gemm_fc1_f32<<<GEMM_GRID, 256, 0, stream>>>(h, fc1w0, Y16);
        } else {
            float* bn2p_prev = bnst + (long)(l - 1) * 8192 + 4096;
            gemm_fc1_bf16<<<GEMM_GRID, 256, 0, stream>>>((const uint_t*)X16,
                fc1w + (long)(l - 1) * 4096, bn2p_prev,
                bn2g + (l - 1) * 64, bn2b + (l - 1) * 64, Y16);
        }
        aggregate<<<3125, 256, 0, stream>>>((const uint_t*)Y16, offs, csr, A_f32, bn1p);
        gemm_fc2<<<GEMM_GRID, 256, 0, stream>>>(A_f32, fc2w + (long)l * 4096, bn1p,
                                                bn1g + l * 64, bn1b + l * 64, X16, bn2p);
        bn_pool<<<391, 256, 0, stream>>>((const uint_t*)X16, bn2p, bn2g + l * 64,
                                         bn2b + l * 64, gid, pl);
    }
    score_kernel<<<64, 256, 0, stream>>>(pooled, pw, pb, out);
}

// Round 7
// 410.754 us; speedup vs baseline: 2.6552x; 1.3320x over previous
//
#include <hip/hip_runtime.h>

#define N_NODES 100000
#define N_EDGES 1600000
#define N_GRAPHS 512
#define D_IN 128
#define D_H 64
#define D_OUT 32
#define N_CONV 4
#define BN_EPS 1e-5f
#define NSLOT 32

#define NB 512        // buckets
#define NPB 196       // nodes per bucket
#define NBUSED 511
#define CHUNK 8192    // edges per binned_scatter block
#define MAXE 4096     // max edges per bucket (mean 3136)

typedef unsigned short ushort_t;
typedef unsigned int uint_t;
typedef __attribute__((ext_vector_type(8))) short bf16x8;
typedef __attribute__((ext_vector_type(4))) float f32x4;
union U4B8 { uint4 u; bf16x8 v; };

__device__ inline float b2f(ushort_t u) {
    union { uint_t i; float f; } c; c.i = ((uint_t)u) << 16; return c.f;
}
__device__ inline ushort_t f2b(float f) {
    union { uint_t i; float f; } c; c.f = f;
    uint_t r = (c.i + 0x7fffu + ((c.i >> 16) & 1u)) >> 16;
    return (ushort_t)r;
}
__device__ inline float blo(uint_t v) { return b2f((ushort_t)(v & 0xffffu)); }
__device__ inline float bhi(uint_t v) { return b2f((ushort_t)(v >> 16)); }

// ---------------- utility: zero a region ------------------------------------
__global__ __launch_bounds__(256) void zero_kernel(int* __restrict__ p, int nwords) {
    int i = blockIdx.x * 256 + threadIdx.x;
    if (i < nwords) p[i] = 0;
}

// ---------------- CSR build: bucket histogram -------------------------------
__global__ __launch_bounds__(256) void bucket_count(const int* __restrict__ dst,
                                                    int* __restrict__ bucketCnt) {
    __shared__ int l[NB];
    int t = threadIdx.x;
    for (int i = t; i < NB; i += 256) l[i] = 0;
    __syncthreads();
    long base = (long)blockIdx.x * 4096;
    for (int i = t; i < 4096; i += 256) {
        long e = base + i;
        if (e < N_EDGES) atomicAdd(&l[(unsigned)dst[e] / NPB], 1);
    }
    __syncthreads();
    for (int i = t; i < NB; i += 256) if (l[i]) atomicAdd(&bucketCnt[i], l[i]);
}

// ---------------- bucket offsets scan ---------------------------------------
__global__ __launch_bounds__(512) void bucket_scan(const int* __restrict__ bucketCnt,
                                                   int* __restrict__ bucketOffs,
                                                   int* __restrict__ bucketCur) {
    __shared__ int s[512];
    int t = threadIdx.x;
    int v = bucketCnt[t];
    s[t] = v;
    __syncthreads();
    for (int off = 1; off < 512; off <<= 1) {
        int u = (t >= off) ? s[t - off] : 0;
        __syncthreads();
        s[t] += u;
        __syncthreads();
    }
    int excl = s[t] - v;
    bucketOffs[t] = excl;
    bucketCur[t] = excl;
    if (t == 511) bucketOffs[512] = s[511];
}

// ---------------- binned scatter: LDS counting-sort by bucket ----------------
__global__ __launch_bounds__(256) void binned_scatter(const int* __restrict__ src,
                                                      const int* __restrict__ dst,
                                                      int* __restrict__ bucketCur,
                                                      uint2* __restrict__ pairs) {
    __shared__ uint2 sorted[CHUNK];          // 64 KB
    __shared__ int lcnt[NB], loffs[NB], lcur[NB], gbase[NB];
    __shared__ int ps[256];
    int t = threadIdx.x;
    long e0 = (long)blockIdx.x * CHUNK;
    int nvalid = (int)min((long)CHUNK, (long)N_EDGES - e0);
    for (int i = t; i < NB; i += 256) lcnt[i] = 0;
    __syncthreads();
    for (int i = t; i < nvalid; i += 256)
        atomicAdd(&lcnt[(unsigned)dst[e0 + i] / NPB], 1);
    __syncthreads();
    int a0 = lcnt[2 * t], a1 = lcnt[2 * t + 1];
    ps[t] = a0 + a1;
    __syncthreads();
    for (int off = 1; off < 256; off <<= 1) {
        int u = (t >= off) ? ps[t - off] : 0;
        __syncthreads();
        ps[t] += u;
        __syncthreads();
    }
    int ex = ps[t] - (a0 + a1);
    loffs[2 * t] = ex; loffs[2 * t + 1] = ex + a0;
    lcur[2 * t] = ex;  lcur[2 * t + 1] = ex + a0;
    __syncthreads();
    for (int i = t; i < NB; i += 256) {
        int c = lcnt[i];
        gbase[i] = c ? atomicAdd(&bucketCur[i], c) : 0;
    }
    for (int i = t; i < nvalid; i += 256) {
        int d = dst[e0 + i];
        int b = (unsigned)d / NPB;
        int pos = atomicAdd(&lcur[b], 1);
        sorted[pos] = make_uint2((unsigned)src[e0 + i], (unsigned)d);
    }
    __syncthreads();
    for (int i = t; i < nvalid; i += 256) {
        uint2 pr = sorted[i];
        int b = pr.y / NPB;
        long gpos = (long)gbase[b] + (i - loffs[b]);
        pairs[gpos] = pr;
    }
}

// ---------------- per-bucket CSR finalize -----------------------------------
__global__ __launch_bounds__(256) void csr_finalize(const uint2* __restrict__ pairs,
                                                    const int* __restrict__ bucketOffs,
                                                    int* __restrict__ offs,
                                                    int* __restrict__ csr) {
    __shared__ uint2 lp[MAXE];     // 32 KB
    __shared__ int lsrc[MAXE];     // 16 KB
    __shared__ int lcnt[NPB], lofs[NPB + 1], lcur[NPB];
    __shared__ int ls[256];
    int b = blockIdx.x, t = threadIdx.x;
    int e0 = bucketOffs[b], e1 = bucketOffs[b + 1];
    int ne = e1 - e0;
    int n0 = b * NPB;
    int nn = min(NPB, N_NODES - n0);
    for (int i = t; i < ne; i += 256) lp[i] = pairs[e0 + i];
    for (int i = t; i < nn; i += 256) lcnt[i] = 0;
    __syncthreads();
    for (int i = t; i < ne; i += 256) atomicAdd(&lcnt[lp[i].y - n0], 1);
    __syncthreads();
    int v = (t < nn) ? lcnt[t] : 0;
    ls[t] = v;
    __syncthreads();
    for (int off = 1; off < 256; off <<= 1) {
        int u = (t >= off) ? ls[t - off] : 0;
        __syncthreads();
        ls[t] += u;
        __syncthreads();
    }
    if (t < nn) { lofs[t] = ls[t] - v; lcur[t] = ls[t] - v; offs[n0 + t] = e0 + ls[t] - v; }
    if (t == 0 && b == NBUSED - 1) offs[N_NODES] = e1;
    __syncthreads();
    for (int i = t; i < ne; i += 256) {
        int pos = atomicAdd(&lcur[lp[i].y - n0], 1);
        lsrc[pos] = (int)lp[i].x;
    }
    __syncthreads();
    for (int i = t; i < ne; i += 256) csr[e0 + i] = lsrc[i];
}

// --------- MFMA GEMM layer0: y16 = bf16(h f32 [N][128]) @ bf16(w) -----------
#define SLABS 4
#define GEMM_BLOCKS 391
__global__ __launch_bounds__(256) void gemm0(const float* __restrict__ in,
                                             const float* __restrict__ w,
                                             ushort_t* __restrict__ y16) {
    __shared__ uint4 Bl[4][4][64];   // 16 KB: [kk][nt][lane] -> 8 bf16
    int t = threadIdx.x;
    for (int idx = t; idx < 4 * 4 * 64; idx += 256) {
        int l = idx & 63, nt = (idx >> 6) & 3, kk = idx >> 8;
        int k0 = kk * 32 + ((l >> 4) << 3), c = nt * 16 + (l & 15);
        uint4 o;
        o.x = (uint_t)f2b(w[(k0 + 0) * 64 + c]) | ((uint_t)f2b(w[(k0 + 1) * 64 + c]) << 16);
        o.y = (uint_t)f2b(w[(k0 + 2) * 64 + c]) | ((uint_t)f2b(w[(k0 + 3) * 64 + c]) << 16);
        o.z = (uint_t)f2b(w[(k0 + 4) * 64 + c]) | ((uint_t)f2b(w[(k0 + 5) * 64 + c]) << 16);
        o.w = (uint_t)f2b(w[(k0 + 6) * 64 + c]) | ((uint_t)f2b(w[(k0 + 7) * 64 + c]) << 16);
        Bl[kk][nt][l] = o;
    }
    __syncthreads();
    int wv = t >> 6, lane = t & 63, lq = lane >> 4, lr = lane & 15;
    bf16x8 B[4][4];
#pragma unroll
    for (int kk = 0; kk < 4; kk++)
#pragma unroll
        for (int nt = 0; nt < 4; nt++) { U4B8 cv; cv.u = Bl[kk][nt][lane]; B[kk][nt] = cv.v; }
    for (int s = 0; s < SLABS; s++) {
        long rb = ((long)blockIdx.x * SLABS + s) * 64 + wv * 16;
        long n = rb + lr;
        const float* rp = in + (n < N_NODES ? n : 0) * 128;
        f32x4 zero = {0.f, 0.f, 0.f, 0.f};
        f32x4 acc[4] = {zero, zero, zero, zero};
#pragma unroll
        for (int kk = 0; kk < 4; kk++) {
            float4 u = *(const float4*)(rp + kk * 32 + lq * 8);
            float4 v = *(const float4*)(rp + kk * 32 + lq * 8 + 4);
            bf16x8 a;
            a[0] = (short)f2b(u.x); a[1] = (short)f2b(u.y);
            a[2] = (short)f2b(u.z); a[3] = (short)f2b(u.w);
            a[4] = (short)f2b(v.x); a[5] = (short)f2b(v.y);
            a[6] = (short)f2b(v.z); a[7] = (short)f2b(v.w);
#pragma unroll
            for (int nt = 0; nt < 4; nt++)
                acc[nt] = __builtin_amdgcn_mfma_f32_16x16x32_bf16(a, B[kk][nt], acc[nt], 0, 0, 0);
        }
#pragma unroll
        for (int nt = 0; nt < 4; nt++)
#pragma unroll
            for (int j = 0; j < 4; j++) {
                long rr = rb + lq * 4 + j;
                if (rr < N_NODES) y16[rr * 64 + nt * 16 + lr] = f2b(acc[nt][j]);
            }
    }
}

// --- MFMA GEMM + fused input BN/relu: out = relu(BN(in_bf16)) @ w ----------
// OSTAT: accumulate output column stats (for fc2 -> bn2p)
template <bool OSTAT>
__global__ __launch_bounds__(256) void gemm_bn(const uint4* __restrict__ in,
                                               const float* __restrict__ w,
                                               const float* __restrict__ bnip,
                                               const float* __restrict__ gi,
                                               const float* __restrict__ bi,
                                               ushort_t* __restrict__ outY,
                                               float* __restrict__ ostat) {
    __shared__ uint4 Bl[2][4][64];   // 8 KB
    __shared__ float sc[64], sh[64];
    __shared__ float red1[4][64], red2[4][64];
    int t = threadIdx.x;
    if (t < 64) {
        float S = 0.f, S2 = 0.f;
        for (int s = 0; s < NSLOT; s++) { S += bnip[s * 128 + t]; S2 += bnip[s * 128 + 64 + t]; }
        float mean = S * (1.f / N_NODES);
        float var = S2 * (1.f / N_NODES) - mean * mean;
        float r = rsqrtf(var + BN_EPS);
        float scv = gi[t] * r;
        sc[t] = scv; sh[t] = bi[t] - mean * scv;
    }
    for (int idx = t; idx < 2 * 4 * 64; idx += 256) {
        int l = idx & 63, nt = (idx >> 6) & 3, kk = idx >> 8;
        int k0 = kk * 32 + ((l >> 4) << 3), c = nt * 16 + (l & 15);
        uint4 o;
        o.x = (uint_t)f2b(w[(k0 + 0) * 64 + c]) | ((uint_t)f2b(w[(k0 + 1) * 64 + c]) << 16);
        o.y = (uint_t)f2b(w[(k0 + 2) * 64 + c]) | ((uint_t)f2b(w[(k0 + 3) * 64 + c]) << 16);
        o.z = (uint_t)f2b(w[(k0 + 4) * 64 + c]) | ((uint_t)f2b(w[(k0 + 5) * 64 + c]) << 16);
        o.w = (uint_t)f2b(w[(k0 + 6) * 64 + c]) | ((uint_t)f2b(w[(k0 + 7) * 64 + c]) << 16);
        Bl[kk][nt][l] = o;
    }
    __syncthreads();
    int wv = t >> 6, lane = t & 63, lq = lane >> 4, lr = lane & 15;
    bf16x8 B[2][4];
#pragma unroll
    for (int kk = 0; kk < 2; kk++)
#pragma unroll
        for (int nt = 0; nt < 4; nt++) { U4B8 cv; cv.u = Bl[kk][nt][lane]; B[kk][nt] = cv.v; }
    float s1[4] = {0.f, 0.f, 0.f, 0.f}, s2[4] = {0.f, 0.f, 0.f, 0.f};
    for (int s = 0; s < SLABS; s++) {
        long rb = ((long)blockIdx.x * SLABS + s) * 64 + wv * 16;
        long n = rb + lr;
        bool ok = n < N_NODES;
        const uint4* rp = in + (ok ? n : 0) * 8;
        f32x4 zero = {0.f, 0.f, 0.f, 0.f};
        f32x4 acc[4] = {zero, zero, zero, zero};
#pragma unroll
        for (int kk = 0; kk < 2; kk++) {
            bf16x8 a;
            if (ok) {
                uint4 v = rp[kk * 4 + lq];
                int k0 = kk * 32 + lq * 8;
                float x0 = fmaxf(blo(v.x) * sc[k0 + 0] + sh[k0 + 0], 0.f);
                float x1 = fmaxf(bhi(v.x) * sc[k0 + 1] + sh[k0 + 1], 0.f);
                float x2 = fmaxf(blo(v.y) * sc[k0 + 2] + sh[k0 + 2], 0.f);
                float x3 = fmaxf(bhi(v.y) * sc[k0 + 3] + sh[k0 + 3], 0.f);
                float x4 = fmaxf(blo(v.z) * sc[k0 + 4] + sh[k0 + 4], 0.f);
                float x5 = fmaxf(bhi(v.z) * sc[k0 + 5] + sh[k0 + 5], 0.f);
                float x6 = fmaxf(blo(v.w) * sc[k0 + 6] + sh[k0 + 6], 0.f);
                float x7 = fmaxf(bhi(v.w) * sc[k0 + 7] + sh[k0 + 7], 0.f);
                a[0] = (short)f2b(x0); a[1] = (short)f2b(x1);
                a[2] = (short)f2b(x2); a[3] = (short)f2b(x3);
                a[4] = (short)f2b(x4); a[5] = (short)f2b(x5);
                a[6] = (short)f2b(x6); a[7] = (short)f2b(x7);
            } else {
#pragma unroll
                for (int j = 0; j < 8; j++) a[j] = 0;
            }
#pragma unroll
            for (int nt = 0; nt < 4; nt++)
                acc[nt] = __builtin_amdgcn_mfma_f32_16x16x32_bf16(a, B[kk][nt], acc[nt], 0, 0, 0);
        }
#pragma unroll
        for (int nt = 0; nt < 4; nt++)
#pragma unroll
            for (int j = 0; j < 4; j++) {
                long rr = rb + lq * 4 + j;
                float val = acc[nt][j];
                if (rr < N_NODES) outY[rr * 64 + nt * 16 + lr] = f2b(val);
                if (OSTAT) { s1[nt] += val; s2[nt] += val * val; }
            }
    }
    if (OSTAT) {
#pragma unroll
        for (int nt = 0; nt < 4; nt++) {
            s1[nt] += __shfl_xor(s1[nt], 16); s1[nt] += __shfl_xor(s1[nt], 32);
            s2[nt] += __shfl_xor(s2[nt], 16); s2[nt] += __shfl_xor(s2[nt], 32);
        }
        if (lq == 0) {
#pragma unroll
            for (int nt = 0; nt < 4; nt++) {
                red1[wv][nt * 16 + lr] = s1[nt];
                red2[wv][nt * 16 + lr] = s2[nt];
            }
        }
        __syncthreads();
        if (t < 64) {
            float S = red1[0][t] + red1[1][t] + red1[2][t] + red1[3][t];
            float S2 = red2[0][t] + red2[1][t] + red2[2][t] + red2[3][t];
            int slot = blockIdx.x & (NSLOT - 1);
            atomicAdd(&ostat[slot * 128 + t], S);
            atomicAdd(&ostat[slot * 128 + 64 + t], S2);
        }
    }
}

// ------- aggregation: agg16(bf16) = y16 + sum_nb y16[nb] + BN1 stats --------
__global__ __launch_bounds__(256) void aggregate(const uint_t* __restrict__ y32,
                                                 const int* __restrict__ offs,
                                                 const int* __restrict__ csr,
                                                 uint_t* __restrict__ aggOut,
                                                 float* __restrict__ bn1p) {
    int t = threadIdx.x;
    int wv = t >> 6, lane = t & 63;
    int g = lane >> 3, l = lane & 7;
    __shared__ float l1[4][64], l2[4][64];
    float st1[8], st2[8];
#pragma unroll
    for (int m = 0; m < 8; m++) { st1[m] = 0.f; st2[m] = 0.f; }
    int nb_base = blockIdx.x * 32 + wv * 8;
    for (int j = 0; j < 8; j++) {
        int n = nb_base + j;
        if (n >= N_NODES) break;
        int p0 = offs[n], p1 = offs[n + 1];
        int cnt = 1 + (p1 - p0);            // self + neighbors
        int rounds = (cnt + 7) >> 3;
        float accA[4] = {0.f, 0.f, 0.f, 0.f}, accB[4] = {0.f, 0.f, 0.f, 0.f};
        int e = g;
        int idx = (e == 0) ? n : ((e < cnt) ? csr[p0 + e - 1] : -1);
        for (int r = 0; r < rounds; r++) {
            int ne = e + 8;
            int nidx = (r + 1 < rounds && ne < cnt) ? csr[p0 + ne - 1] : -1;
            if (idx >= 0) {
                uint4 v = *(const uint4*)(y32 + (long)idx * 32 + 4 * l);
                accA[0] += __uint_as_float(v.x << 16);
                accB[0] += __uint_as_float(v.x & 0xffff0000u);
                accA[1] += __uint_as_float(v.y << 16);
                accB[1] += __uint_as_float(v.y & 0xffff0000u);
                accA[2] += __uint_as_float(v.z << 16);
                accB[2] += __uint_as_float(v.z & 0xffff0000u);
                accA[3] += __uint_as_float(v.w << 16);
                accB[3] += __uint_as_float(v.w & 0xffff0000u);
            }
            e = ne; idx = nidx;
        }
#pragma unroll
        for (int m = 0; m < 4; m++) {
            accA[m] += __shfl_xor(accA[m], 8);
            accB[m] += __shfl_xor(accB[m], 8);
            accA[m] += __shfl_xor(accA[m], 16);
            accB[m] += __shfl_xor(accB[m], 16);
            accA[m] += __shfl_xor(accA[m], 32);
            accB[m] += __shfl_xor(accB[m], 32);
        }
        if (g == 0) {
            uint4 o;
            o.x = (uint_t)f2b(accA[0]) | ((uint_t)f2b(accB[0]) << 16);
            o.y = (uint_t)f2b(accA[1]) | ((uint_t)f2b(accB[1]) << 16);
            o.z = (uint_t)f2b(accA[2]) | ((uint_t)f2b(accB[2]) << 16);
            o.w = (uint_t)f2b(accA[3]) | ((uint_t)f2b(accB[3]) << 16);
            *(uint4*)&aggOut[(long)n * 32 + 4 * l] = o;
            st1[0] += accA[0]; st2[0] += accA[0] * accA[0];
            st1[1] += accB[0]; st2[1] += accB[0] * accB[0];
            st1[2] += accA[1]; st2[2] += accA[1] * accA[1];
            st1[3] += accB[1]; st2[3] += accB[1] * accB[1];
            st1[4] += accA[2]; st2[4] += accA[2] * accA[2];
            st1[5] += accB[2]; st2[5] += accB[2] * accB[2];
            st1[6] += accA[3]; st2[6] += accA[3] * accA[3];
            st1[7] += accB[3]; st2[7] += accB[3] * accB[3];
        }
    }
    if (g == 0) {
#pragma unroll
        for (int m = 0; m < 8; m++) { l1[wv][8 * l + m] = st1[m]; l2[wv][8 * l + m] = st2[m]; }
    }
    __syncthreads();
    if (t < 64) {
        float S = l1[0][t] + l1[1][t] + l1[2][t] + l1[3][t];
        float S2 = l2[0][t] + l2[1][t] + l2[2][t] + l2[3][t];
        int slot = blockIdx.x & (NSLOT - 1);
        atomicAdd(&bn1p[slot * 128 + t], S);
        atomicAdd(&bn1p[slot * 128 + 64 + t], S2);
    }
}

// --- pooled[g] += relu(BN2(h2)) (sorted graph_ids) --------------------------
__global__ __launch_bounds__(256) void bn_pool(const uint_t* __restrict__ h2,
                                               const float* __restrict__ bn2p,
                                               const float* __restrict__ g2,
                                               const float* __restrict__ b2,
                                               const int* __restrict__ gid,
                                               float* __restrict__ pooled) {
    __shared__ float sc[64], sh[64];
    int t = threadIdx.x;
    if (t < 64) {
        float S = 0.f, S2 = 0.f;
        for (int s = 0; s < NSLOT; s++) { S += bn2p[s * 128 + t]; S2 += bn2p[s * 128 + 64 + t]; }
        float mean = S * (1.f / N_NODES);
        float var = S2 * (1.f / N_NODES) - mean * mean;
        float r = rsqrtf(var + BN_EPS);
        float scv = g2[t] * r;
        sc[t] = scv; sh[t] = b2[t] - mean * scv;
    }
    __syncthreads();
    int c = t & 31, rs = t >> 5;
    float sA = sc[2 * c], hA = sh[2 * c], sB = sc[2 * c + 1], hB = sh[2 * c + 1];
    long base = (long)blockIdx.x * 256;
    float pa = 0.f, pb2 = 0.f; int gc = -1;
    for (int i = 0; i < 32; i++) {
        long n = base + rs + 8 * i;
        if (n >= N_NODES) break;
        int g = gid[n];
        uint_t v = h2[n * 32 + c];
        float x0 = fmaxf(blo(v) * sA + hA, 0.f);
        float x1 = fmaxf(bhi(v) * sB + hB, 0.f);
        if (g != gc) {
            if (gc >= 0) {
                atomicAdd(&pooled[(long)gc * 64 + 2 * c], pa);
                atomicAdd(&pooled[(long)gc * 64 + 2 * c + 1], pb2);
            }
            gc = g; pa = 0.f; pb2 = 0.f;
        }
        pa += x0; pb2 += x1;
    }
    if (gc >= 0) {
        atomicAdd(&pooled[(long)gc * 64 + 2 * c], pa);
        atomicAdd(&pooled[(long)gc * 64 + 2 * c + 1], pb2);
    }
}

// --------- score = sum_l pooled_l @ pred_w_l + pred_b_l --------------------
__global__ __launch_bounds__(256) void score_kernel(const float* __restrict__ pooled,
                                                    const float* __restrict__ pw,
                                                    const float* __restrict__ pb,
                                                    float* __restrict__ out) {
    int idx = blockIdx.x * 256 + threadIdx.x;  // 16384 = 512*32
    int g = idx >> 5, o = idx & 31;
    float acc = 0.f;
    for (int l = 0; l < N_CONV; l++) {
        acc += pb[l * 32 + o];
        const float* pr = pooled + (long)l * N_GRAPHS * 64 + (long)g * 64;
        const float* wr = pw + l * 64 * 32;
        for (int k = 0; k < 64; k++) acc += pr[k] * wr[k * 32 + o];
    }
    out[idx] = acc;
}

extern "C" void kernel_launch(void* const* d_in, const int* in_sizes, int n_in,
                              void* d_out, int out_size, void* d_ws, size_t ws_size,
                              hipStream_t stream) {
    const float* h     = (const float*)d_in[0];
    const int*   src   = (const int*)d_in[1];
    const int*   dst   = (const int*)d_in[2];
    const int*   gid   = (const int*)d_in[3];
    const float* fc1w0 = (const float*)d_in[4];
    const float* fc1w  = (const float*)d_in[5];
    const float* fc2w  = (const float*)d_in[6];
    const float* bn1g  = (const float*)d_in[7];
    const float* bn1b  = (const float*)d_in[8];
    const float* bn2g  = (const float*)d_in[9];
    const float* bn2b  = (const float*)d_in[10];
    const float* pw    = (const float*)d_in[11];
    const float* pb    = (const float*)d_in[12];
    float* out = (float*)d_out;

    char* ws = (char*)d_ws;
    uint_t*   AGG16   = (uint_t*)  (ws);              // agg bf16: 12,800,000
    uint2*    pairs   = (uint2*)   (ws);              // 12,800,000 (alias; dead before layer-0 aggregate)
    ushort_t* X16     = (ushort_t*)(ws + 25600000);   // h2 bf16: 12,800,000
    ushort_t* Y16     = (ushort_t*)(ws + 38400000);   // y bf16: 12,800,000
    float*    bnst    = (float*)   (ws + 51200000);   // 131,072
    float*    pooled  = (float*)   (ws + 51331072);   // 524,288
    int*   bucketCnt  = (int*)     (ws + 51855360);   // 2,048
    int*   bucketOffs = (int*)     (ws + 51857408);   // 2,052
    int*   bucketCur  = (int*)     (ws + 51859460);   // 2,048
    int*   offs       = (int*)     (ws + 51861508);   // 400,004
    int*   csr        = (int*)     (ws + 52261512);   // 6,400,000 (end 58,661,512)

    // zero: bnst + pooled + bucketCnt (contiguous: 51,200,000 .. 51,857,408)
    const int zwords = (51857408 - 51200000) / 4;     // 164,352
    zero_kernel<<<(zwords + 255) / 256, 256, 0, stream>>>((int*)bnst, zwords);

    bucket_count<<<(N_EDGES + 4095) / 4096, 256, 0, stream>>>(dst, bucketCnt);
    bucket_scan<<<1, 512, 0, stream>>>(bucketCnt, bucketOffs, bucketCur);
    binned_scatter<<<(N_EDGES + CHUNK - 1) / CHUNK, 256, 0, stream>>>(src, dst, bucketCur, pairs);
    csr_finalize<<<NBUSED, 256, 0, stream>>>(pairs, bucketOffs, offs, csr);

    for (int l = 0; l < N_CONV; l++) {
        float* bn1p = bnst + (long)l * 8192;
        float* bn2p = bn1p + 4096;
        float* pl = pooled + (long)l * N_GRAPHS * 64;
        if (l == 0) {
            gemm0<<<GEMM_BLOCKS, 256, 0, stream>>>(h, fc1w0, Y16);
        } else {
            float* bn2p_prev = bnst + (long)(l - 1) * 8192 + 4096;
            gemm_bn<false><<<GEMM_BLOCKS, 256, 0, stream>>>((const uint4*)X16,
                fc1w + (long)(l - 1) * 4096, bn2p_prev,
                bn2g + (l - 1) * 64, bn2b + (l - 1) * 64, Y16, (float*)nullptr);
        }
        aggregate<<<3125, 256, 0, stream>>>((const uint_t*)Y16, offs, csr, AGG16, bn1p);
        gemm_bn<true><<<GEMM_BLOCKS, 256, 0, stream>>>((const uint4*)AGG16,
            fc2w + (long)l * 4096, bn1p, bn1g + l * 64, bn1b + l * 64, X16, bn2p);
        bn_pool<<<391, 256, 0, stream>>>((const uint_t*)X16, bn2p, bn2g + l * 64,
                                         bn2b + l * 64, gid, pl);
    }
    score_kernel<<<64, 256, 0, stream>>>(pooled, pw, pb, out);
}